// Round 5
// baseline (369.459 us; speedup 1.0000x reference)
//
#include <hip/hip_runtime.h>
#include <math.h>

#define NB 64
#define TC 16
#define HC 32
#define NNODES 16384
#define NEDGES 131072
#define EPSV 1e-15f

static inline int GRID(int n) { return (n + 255) / 256; }

template<int V> struct Log2 { static constexpr int v = 1 + Log2<V/2>::v; };
template<> struct Log2<1> { static constexpr int v = 0; };

// ---------------- GCN conv front-end ----------------

__global__ void k_init_deg(float* deg) {
    int i = blockIdx.x * 256 + threadIdx.x;
    if (i < NNODES) deg[i] = 1.0f;   // self-loop weight
}

__global__ void k_edge_deg(const int* __restrict__ dst, const float* __restrict__ ew,
                           float* __restrict__ deg) {
    int e = blockIdx.x * 256 + threadIdx.x;
    if (e < NEDGES) atomicAdd(&deg[dst[e]], ew[e]);
}

__global__ void k_rsqrt(float* deg) {
    int i = blockIdx.x * 256 + threadIdx.x;
    if (i < NNODES) { float d = deg[i]; deg[i] = (d > 0.f) ? rsqrtf(d) : 0.f; }
}

// fused: unweighted adj count (for mincut) + weighted adj coef (for GCN gather)
__global__ void k_build(const int* __restrict__ src, const int* __restrict__ dst,
                        const float* __restrict__ ew, const float* __restrict__ dinv,
                        float* __restrict__ adj, float* __restrict__ wadj) {
    int e = blockIdx.x * 256 + threadIdx.x;
    if (e >= NEDGES) return;
    int s = src[e], d = dst[e];
    int g = s >> 8, sl = s & 255, dl = d & 255;
    atomicAdd(&adj[((size_t)g << 16) + (sl << 8) + dl], 1.0f);
    float coef = dinv[s] * ew[e] * dinv[d];
    atomicAdd(&wadj[((size_t)g << 16) + (dl << 8) + sl], coef);
}

// z[b,d,0:48] = sum_s wadj[b,d,s] * pos[b,s,0:48]
__global__ void k_zgemm(const float* __restrict__ wadj, const float* __restrict__ pos,
                        float* __restrict__ z) {
    __shared__ __align__(16) float as_[64 * 36];
    __shared__ __align__(16) float bs[32 * 48];
    int b = blockIdx.x >> 2;
    int dtile = (blockIdx.x & 3) * 64;
    int tid = threadIdx.x;
    int d = tid >> 2, q = tid & 3;
    float acc[12];
#pragma unroll
    for (int j = 0; j < 12; ++j) acc[j] = 0.f;
    const float* arow = wadj + ((size_t)b << 16) + (size_t)dtile * 256;
    const float* pbase = pos + (size_t)b * 256 * 48;
    for (int s0 = 0; s0 < 256; s0 += 32) {
        for (int i = tid; i < 512; i += 256) {
            int r = i >> 3, c = i & 7;
            *(float4*)(as_ + r * 36 + c * 4) =
                *(const float4*)(arow + (size_t)r * 256 + s0 + c * 4);
        }
        for (int i = tid; i < 384; i += 256) {
            int r = i / 12, c = i % 12;
            *(float4*)(bs + r * 48 + c * 4) =
                *(const float4*)(pbase + (size_t)(s0 + r) * 48 + c * 4);
        }
        __syncthreads();
#pragma unroll 8
        for (int sp = 0; sp < 32; ++sp) {
            float a = as_[d * 36 + sp];
            const float* bp = &bs[sp * 48 + q * 12];
#pragma unroll
            for (int j = 0; j < 12; ++j) acc[j] += a * bp[j];
        }
        __syncthreads();
    }
    float* zr = z + (size_t)(b * 256 + dtile + d) * 48 + q * 12;
#pragma unroll
    for (int j = 0; j < 12; ++j) zr[j] = acc[j];
}

// Fused per-node: y = relu((z + pos*dinv^2)@W1 + b1)  [write X]
//                 xm = mean_t y ; s1 = tanh(xm@Wp1+bp1) ; p1 = softmax(s1)
__global__ __launch_bounds__(512) void k_y2(
        const float* __restrict__ z, const float* __restrict__ pos,
        const float* __restrict__ dinv, const float* __restrict__ W1,
        const float* __restrict__ b1, const float* __restrict__ Wp1,
        const float* __restrict__ bp1, float* __restrict__ y,
        float* __restrict__ p1) {
    __shared__ float ys[16][33];
    __shared__ __align__(16) float wp[32 * 64];
    __shared__ float xmv[32];
    int n = blockIdx.x;
    int tid = threadIdx.x;
    int t = tid >> 5, h = tid & 31;
    ((float4*)wp)[tid] = ((const float4*)Wp1)[tid];      // 512 float4 = 2048 floats
    const float* zr = z + (size_t)n * 48 + t * 3;
    const float* pr = pos + (size_t)n * 48 + t * 3;
    float di = dinv[n], d2 = di * di;
    float a0 = zr[0] + pr[0] * d2;
    float a1 = zr[1] + pr[1] * d2;
    float a2 = zr[2] + pr[2] * d2;
    float v = fmaxf(a0 * W1[h] + a1 * W1[32 + h] + a2 * W1[64 + h] + b1[h], 0.f);
    y[(size_t)n * 512 + tid] = v;
    ys[t][h] = v;
    __syncthreads();
    if (tid < 32) {
        float s = 0.f;
#pragma unroll
        for (int tt = 0; tt < 16; ++tt) s += ys[tt][tid];
        xmv[tid] = s * (1.0f / 16.0f);
    }
    __syncthreads();
    if (tid < 64) {
        float acc = bp1[tid];
#pragma unroll 8
        for (int hh = 0; hh < 32; ++hh) acc += xmv[hh] * wp[hh * 64 + tid];
        float vv = tanhf(acc);
        float m = vv;
        for (int o = 32; o > 0; o >>= 1) m = fmaxf(m, __shfl_xor(m, o));
        float e = expf(vv - m);
        float s = e;
        for (int o = 32; o > 0; o >>= 1) s += __shfl_xor(s, o);
        p1[(size_t)n * 64 + tid] = e / s;
    }
}

// ---------------- level kernels ----------------

// xm[r,h] = mean_t x[...]  (L2/L3 only)
__global__ void k_mean_t(const float* __restrict__ x, float* __restrict__ xm,
                         int Nc, int sb, int st, int sn) {
    int idx = blockIdx.x * 256 + threadIdx.x;
    int total = NB * Nc * HC;
    if (idx >= total) return;
    int h = idx & 31;
    int r = idx >> 5;
    int b = r / Nc, n = r % Nc;
    const float* p = x + (size_t)b * sb + (size_t)n * sn + h;
    float s = 0.f;
    for (int t = 0; t < TC; ++t) s += p[(size_t)t * st];
    xm[idx] = s * (1.0f / TC);
}

// one 64-lane wave per row: s = tanh(xm@Wp + bp), p = softmax_k(s)
__global__ void k_s_softmax(const float* __restrict__ xm, const float* __restrict__ Wp,
                            const float* __restrict__ bp, float* __restrict__ p, int Kc) {
    int r = blockIdx.x;
    int k = threadIdx.x;
    const float* xr = xm + (size_t)r * HC;
    float v = -1e30f;
    if (k < Kc) {
        float acc = bp[k];
        for (int h = 0; h < HC; ++h) acc += xr[h] * Wp[h * Kc + k];
        v = tanhf(acc);
    }
    float m = v;
    for (int o = 32; o > 0; o >>= 1) m = fmaxf(m, __shfl_xor(m, o));
    float e = (k < Kc) ? expf(v - m) : 0.f;
    float s = e;
    for (int o = 32; o > 0; o >>= 1) s += __shfl_xor(s, o);
    if (k < Kc) p[(size_t)r * Kc + k] = e / s;
}

// out[b,t,k,h] = sum_n p[(b*NC+n)*KC+k] * x[b*SB + t*STT + n*STN + h]
template<int NC, int KC, int NCH, int SB, int STT, int STN>
__global__ void k_pool_t(const float* __restrict__ p, const float* __restrict__ x,
                         float* __restrict__ outp) {
    constexpr int KPT = KC / 8;
    __shared__ __align__(16) float xs[NCH * HC];
    __shared__ __align__(16) float ps[NCH * KC];
    int bt = blockIdx.x;
    int b = bt >> 4, t = bt & 15;
    int tid = threadIdx.x;
    int h = tid & 31;
    int k0 = (tid >> 5) * KPT;
    float acc[KPT];
#pragma unroll
    for (int j = 0; j < KPT; ++j) acc[j] = 0.f;
    const float* xbase = x + (size_t)b * SB + (size_t)t * STT;
    const float* pbase = p + (size_t)b * NC * KC;
    for (int n0 = 0; n0 < NC; n0 += NCH) {
        for (int i = tid; i < NCH * 8; i += 256) {
            int n = i >> 3, q = i & 7;
            ((float4*)xs)[i] = ((const float4*)(xbase + (size_t)(n0 + n) * STN))[q];
        }
        for (int i = tid; i < NCH * KC / 4; i += 256)
            ((float4*)ps)[i] = ((const float4*)(pbase + (size_t)n0 * KC))[i];
        __syncthreads();
#pragma unroll 4
        for (int n = 0; n < NCH; ++n) {
            float xv = xs[n * HC + h];
#pragma unroll
            for (int j = 0; j < KPT; ++j) acc[j] += ps[n * KC + k0 + j] * xv;
        }
        __syncthreads();
    }
#pragma unroll
    for (int j = 0; j < KPT; ++j)
        outp[((size_t)bt * KC + k0 + j) * HC + h] = acc[j];
}

__global__ void k_dflat(const float* __restrict__ adj, float* __restrict__ dflat, int Nc) {
    int idx = blockIdx.x * 256 + threadIdx.x;
    if (idx >= NB * Nc) return;
    const float* a = adj + (size_t)idx * Nc;
    float s = 0.f;
    for (int m = 0; m < Nc; ++m) s += a[m];
    dflat[idx] = s;
}

// tmp[b,n,l] = sum_m adj[b,n,m]*p[b,m,l]; block per (b, 32-n tile), LDS staged
template<int NC, int KC, int MCH>
__global__ void k_adjp_t(const float* __restrict__ adj, const float* __restrict__ p,
                         float* __restrict__ tmp) {
    constexpr int LPT = KC / 8;
    constexpr int MROW = MCH + 4;
    constexpr int MQ = MCH / 4;
    constexpr int NBK = NC / 32;
    __shared__ __align__(16) float ps[MCH * KC];
    __shared__ __align__(16) float as_[32 * MROW];
    int b = blockIdx.x / NBK;
    int nt0 = (blockIdx.x % NBK) * 32;
    int tid = threadIdx.x;
    int n = tid >> 3;
    int l0 = (tid & 7) * LPT;
    float acc[LPT];
#pragma unroll
    for (int j = 0; j < LPT; ++j) acc[j] = 0.f;
    for (int m0 = 0; m0 < NC; m0 += MCH) {
        for (int i = tid; i < MCH * KC / 4; i += 256)
            ((float4*)ps)[i] = ((const float4*)(p + ((size_t)b * NC + m0) * KC))[i];
        for (int i = tid; i < 32 * MQ; i += 256) {
            int r = i / MQ, q = i % MQ;
            ((float4*)(as_ + r * MROW))[q] =
                ((const float4*)(adj + ((size_t)b * NC + nt0 + r) * NC + m0))[q];
        }
        __syncthreads();
#pragma unroll 4
        for (int m = 0; m < MCH; ++m) {
            float av = as_[n * MROW + m];
#pragma unroll
            for (int j = 0; j < LPT; ++j) acc[j] += av * ps[m * KC + l0 + j];
        }
        __syncthreads();
    }
#pragma unroll
    for (int j = 0; j < LPT; ++j)
        tmp[((size_t)b * NC + nt0 + n) * KC + l0 + j] = acc[j];
}

__device__ inline float blk_sum256(float v, float* rbuf) {
    for (int o = 32; o > 0; o >>= 1) v += __shfl_xor(v, o);
    __syncthreads();
    if ((threadIdx.x & 63) == 0) rbuf[threadIdx.x >> 6] = v;
    __syncthreads();
    return rbuf[0] + rbuf[1] + rbuf[2] + rbuf[3];
}

// Partial GEMM: G[b] += p_chunk^T @ [p_chunk | tmp_chunk], den[b] += sum p^2*deg
// grid = NB * NSPLIT; requires KC/KT == 16 and 2*KC/LT == 16
template<int NC, int KC, int NSPLIT, int KT, int LT>
__global__ void k_ssg(const float* __restrict__ p, const float* __restrict__ tmp,
                      const float* __restrict__ dflat, float* __restrict__ G,
                      float* __restrict__ Gden) {
    constexpr int NCH = NC / NSPLIT;
    constexpr int LC = 2 * KC;
    constexpr int KQ = KC / 4;
    __shared__ __align__(16) float ab[NCH * LC];
    __shared__ float rbuf[4];
    int b = blockIdx.x / NSPLIT;
    int n0 = (blockIdx.x % NSPLIT) * NCH;
    int tid = threadIdx.x;
    const float* pb = p + ((size_t)b * NC + n0) * KC;
    const float* tb = tmp + ((size_t)b * NC + n0) * KC;
    const float* db = dflat + (size_t)b * NC + n0;
    for (int i = tid; i < NCH * KQ; i += 256) {
        int r = i / KQ, c = i % KQ;
        *(float4*)(ab + r * LC + c * 4) = ((const float4*)pb)[i];
        *(float4*)(ab + r * LC + KC + c * 4) = ((const float4*)tb)[i];
    }
    __syncthreads();
    float den = 0.f;
    for (int i = tid; i < NCH * KQ; i += 256) {
        int r = i / KQ, c = i % KQ;
        float4 v = *(const float4*)(ab + r * LC + c * 4);
        den += (v.x * v.x + v.y * v.y + v.z * v.z + v.w * v.w) * db[r];
    }
    int kt = tid >> 4, lt = tid & 15;
    int k0 = kt * KT, l0 = lt * LT;
    float acc[KT][LT];
#pragma unroll
    for (int r = 0; r < KT; ++r)
#pragma unroll
        for (int c = 0; c < LT; ++c) acc[r][c] = 0.f;
#pragma unroll 4
    for (int n = 0; n < NCH; ++n) {
        float kv[KT], lv[LT];
#pragma unroll
        for (int r = 0; r < KT; ++r) kv[r] = ab[n * LC + k0 + r];
#pragma unroll
        for (int c = 0; c < LT; ++c) lv[c] = ab[n * LC + l0 + c];
#pragma unroll
        for (int r = 0; r < KT; ++r)
#pragma unroll
            for (int c = 0; c < LT; ++c) acc[r][c] += kv[r] * lv[c];
    }
    float* Gb = G + (size_t)b * (KC * LC);
#pragma unroll
    for (int r = 0; r < KT; ++r)
#pragma unroll
        for (int c = 0; c < LT; ++c)
            atomicAdd(&Gb[(k0 + r) * LC + l0 + c], acc[r][c]);
    float dt = blk_sum256(den, rbuf);
    if (tid == 0) atomicAdd(&Gden[b], dt);
}

// Per-batch finish: losses from G/Gden, zero-diag + normalize -> oadj_out, next dflat
template<int KC, bool DFN>
__global__ void k_finish(const float* __restrict__ G, const float* __restrict__ Gden,
                         float* __restrict__ oadj_out, float* __restrict__ dfn_out,
                         float* __restrict__ mc_out, float* __restrict__ or_out) {
    constexpr int LK = Log2<KC>::v;
    constexpr int KCP = KC + 1;
    constexpr int LC = 2 * KC;
    __shared__ float sss[KC * KCP];
    __shared__ float oss[KC * KCP];
    __shared__ float dvv[KC];
    __shared__ float rbuf[4];
    int b = blockIdx.x, tid = threadIdx.x;
    const float* Gb = G + (size_t)b * KC * LC;
    for (int i = tid; i < KC * KC; i += 256) {
        int k = i >> LK, l = i & (KC - 1);
        sss[k * KCP + l] = Gb[k * LC + l];
        oss[k * KCP + l] = Gb[k * LC + KC + l];
    }
    __syncthreads();
    float ssn2 = 0.f;
    for (int i = tid; i < KC * KC; i += 256) {
        int k = i >> LK, l = i & (KC - 1);
        float v = sss[k * KCP + l];
        ssn2 += v * v;
    }
    float num = 0.f;
    for (int k = tid; k < KC; k += 256) num += oss[k * KCP + k];
    float ssn2_t = blk_sum256(ssn2, rbuf);
    float num_t = blk_sum256(num, rbuf);
    float den_t = Gden[b];
    float inv = 1.0f / sqrtf(ssn2_t);
    float dk = rsqrtf((float)KC);
    float o2 = 0.f;
    for (int i = tid; i < KC * KC; i += 256) {
        int k = i >> LK, l = i & (KC - 1);
        float v = sss[k * KCP + l] * inv - ((k == l) ? dk : 0.f);
        o2 += v * v;
    }
    float o2_t = blk_sum256(o2, rbuf);
    if (tid == 0) {
        atomicAdd(mc_out, -(num_t / den_t) * (1.0f / NB));
        atomicAdd(or_out, sqrtf(o2_t) * (1.0f / NB));
    }
    if (tid < KC) {
        float rs = 0.f;
        for (int l = 0; l < KC; ++l) rs += oss[tid * KCP + l];
        rs -= oss[tid * KCP + tid];
        dvv[tid] = sqrtf(rs) + EPSV;
    }
    __syncthreads();
    for (int i = tid; i < KC * KC; i += 256) {
        int k = i >> LK, l = i & (KC - 1);
        float v = (k == l) ? 0.f : oss[k * KCP + l] / (dvv[k] * dvv[l]);
        oadj_out[(size_t)b * KC * KC + i] = v;
    }
    if (DFN && tid < KC) {
        float s = 0.f;
        for (int l = 0; l < KC; ++l)
            if (l != tid) s += oss[tid * KCP + l] / (dvv[tid] * dvv[l]);
        dfn_out[(size_t)b * KC + tid] = s;
    }
}

// single-block post for tiny L3 (Nc=32, Kc=8)
template<int NC, int KC, int NCH, bool DFN>
__global__ void k_post_t(const float* __restrict__ p, const float* __restrict__ tmp,
                         const float* __restrict__ dflat, float* __restrict__ oadj_out,
                         float* __restrict__ dfn_out, float* __restrict__ mc_out,
                         float* __restrict__ or_out) {
    constexpr int LK = Log2<KC>::v;
    constexpr int KCP = KC + 1;
    constexpr int TW = KC / 4;
    constexpr int NT = TW * TW;
    __shared__ __align__(16) float ps[NCH * KC];
    __shared__ __align__(16) float ts[NCH * KC];
    __shared__ float sss[KC * KCP];
    __shared__ float oss[KC * KCP];
    __shared__ float dvv[KC];
    __shared__ float rbuf[4];
    int b = blockIdx.x, tid = threadIdx.x;
    const float* pb = p + (size_t)b * NC * KC;
    const float* tb = tmp + (size_t)b * NC * KC;
    const float* db = dflat + (size_t)b * NC;
    float sa[4][4], oa[4][4];
#pragma unroll
    for (int r = 0; r < 4; ++r)
#pragma unroll
        for (int c = 0; c < 4; ++c) { sa[r][c] = 0.f; oa[r][c] = 0.f; }
    int kt = (tid < NT) ? tid / TW : 0;
    int lt = (tid < NT) ? tid % TW : 0;
    float den = 0.f;
    for (int n0 = 0; n0 < NC; n0 += NCH) {
        for (int i = tid; i < NCH * KC / 4; i += 256) {
            ((float4*)ps)[i] = ((const float4*)(pb + (size_t)n0 * KC))[i];
            ((float4*)ts)[i] = ((const float4*)(tb + (size_t)n0 * KC))[i];
        }
        __syncthreads();
        for (int i4 = tid; i4 < NCH * KC / 4; i4 += 256) {
            float4 v = ((const float4*)ps)[i4];
            float dd = db[n0 + ((i4 * 4) >> LK)];
            den += (v.x * v.x + v.y * v.y + v.z * v.z + v.w * v.w) * dd;
        }
        if (tid < NT) {
#pragma unroll 4
            for (int nn = 0; nn < NCH; ++nn) {
                float4 kv4 = *(const float4*)&ps[nn * KC + kt * 4];
                float4 lv4 = *(const float4*)&ps[nn * KC + lt * 4];
                float4 tv4 = *(const float4*)&ts[nn * KC + lt * 4];
                float kv[4] = {kv4.x, kv4.y, kv4.z, kv4.w};
                float lv[4] = {lv4.x, lv4.y, lv4.z, lv4.w};
                float tv[4] = {tv4.x, tv4.y, tv4.z, tv4.w};
#pragma unroll
                for (int r = 0; r < 4; ++r)
#pragma unroll
                    for (int c = 0; c < 4; ++c) {
                        sa[r][c] += kv[r] * lv[c];
                        oa[r][c] += kv[r] * tv[c];
                    }
            }
        }
        __syncthreads();
    }
    if (tid < NT) {
#pragma unroll
        for (int r = 0; r < 4; ++r)
#pragma unroll
            for (int c = 0; c < 4; ++c) {
                sss[(kt * 4 + r) * KCP + lt * 4 + c] = sa[r][c];
                oss[(kt * 4 + r) * KCP + lt * 4 + c] = oa[r][c];
            }
    }
    __syncthreads();
    float ssn2 = 0.f;
    for (int i = tid; i < KC * KC; i += 256) {
        int k = i >> LK, l = i & (KC - 1);
        float v = sss[k * KCP + l];
        ssn2 += v * v;
    }
    float num = 0.f;
    for (int k = tid; k < KC; k += 256) num += oss[k * KCP + k];
    float den_t = blk_sum256(den, rbuf);
    float ssn2_t = blk_sum256(ssn2, rbuf);
    float num_t = blk_sum256(num, rbuf);
    float inv = 1.0f / sqrtf(ssn2_t);
    float dk = rsqrtf((float)KC);
    float o2 = 0.f;
    for (int i = tid; i < KC * KC; i += 256) {
        int k = i >> LK, l = i & (KC - 1);
        float v = sss[k * KCP + l] * inv - ((k == l) ? dk : 0.f);
        o2 += v * v;
    }
    float o2_t = blk_sum256(o2, rbuf);
    if (tid == 0) {
        atomicAdd(mc_out, -(num_t / den_t) * (1.0f / NB));
        atomicAdd(or_out, sqrtf(o2_t) * (1.0f / NB));
    }
    if (tid < KC) {
        float rs = 0.f;
        for (int l = 0; l < KC; ++l) rs += oss[tid * KCP + l];
        rs -= oss[tid * KCP + tid];
        dvv[tid] = sqrtf(rs) + EPSV;
    }
    __syncthreads();
    for (int i = tid; i < KC * KC; i += 256) {
        int k = i >> LK, l = i & (KC - 1);
        float v = (k == l) ? 0.f : oss[k * KCP + l] / (dvv[k] * dvv[l]);
        oadj_out[(size_t)b * KC * KC + i] = v;
    }
    if (DFN && tid < KC) {
        float s = 0.f;
        for (int l = 0; l < KC; ++l)
            if (l != tid) s += oss[tid * KCP + l] / (dvv[tid] * dvv[l]);
        dfn_out[(size_t)b * KC + tid] = s;
    }
}

// Fused dense_graph_conv per (b,t): out = (adjn@x)@Wrel + brel + x@Wroot
template<int NC2, int OC>
__global__ void k_graphconv_t(const float* __restrict__ adjn, const float* __restrict__ x,
                              const float* __restrict__ Wrel, const float* __restrict__ brel,
                              const float* __restrict__ Wroot, float* __restrict__ outp) {
    constexpr int EL1 = NC2 * HC / 256;
    constexpr int EL2 = NC2 * OC / 256;
    constexpr int LOC = Log2<OC>::v;
    __shared__ __align__(16) float xs[NC2 * HC];
    __shared__ __align__(16) float as_[NC2 * NC2];
    __shared__ float c1[NC2 * HC];
    int bt = blockIdx.x;
    int b = bt >> 4;
    int tid = threadIdx.x;
    for (int i = tid; i < NC2 * HC / 4; i += 256)
        ((float4*)xs)[i] = ((const float4*)(x + (size_t)bt * NC2 * HC))[i];
    for (int i = tid; i < NC2 * NC2 / 4; i += 256)
        ((float4*)as_)[i] = ((const float4*)(adjn + (size_t)b * NC2 * NC2))[i];
    __syncthreads();
#pragma unroll
    for (int e = 0; e < EL1; ++e) {
        int idx = tid + e * 256;
        int hh = idx & 31, n = idx >> 5;
        float acc = 0.f;
#pragma unroll 8
        for (int m = 0; m < NC2; ++m) acc += as_[n * NC2 + m] * xs[m * HC + hh];
        c1[idx] = acc;
    }
    __syncthreads();
#pragma unroll
    for (int e = 0; e < EL2; ++e) {
        int idx = tid + e * 256;
        int o = idx & (OC - 1), n = idx >> LOC;
        float acc = brel[o];
#pragma unroll 8
        for (int hh = 0; hh < HC; ++hh)
            acc += c1[n * HC + hh] * Wrel[hh * OC + o] + xs[n * HC + hh] * Wroot[hh * OC + o];
        outp[(size_t)bt * NC2 * OC + idx] = acc;
    }
}

// q[b,k,m] = sum_l p2[b,k,l] * p3[b,l,m]
__global__ void k_p23(const float* __restrict__ p2, const float* __restrict__ p3,
                      float* __restrict__ q) {
    int idx = blockIdx.x * 256 + threadIdx.x;
    if (idx >= NB * 64 * 8) return;
    int m = idx & 7;
    int rest = idx >> 3;
    int k = rest % 64;
    int b = rest / 64;
    const float* p2p = p2 + ((size_t)b * 64 + k) * 32;
    const float* p3p = p3 + (size_t)b * 32 * 8 + m;
    float s = 0.f;
    for (int l = 0; l < 32; ++l) s += p2p[l] * p3p[(size_t)l * 8];
    q[idx] = s;
}

// aggout[b,n,m] = sum_k p1[b,n,k] * q[b,k,m]
__global__ void k_aggout(const float* __restrict__ p1, const float* __restrict__ q,
                         float* __restrict__ outp) {
    int idx = blockIdx.x * 256 + threadIdx.x;
    if (idx >= NB * 256 * 8) return;
    int m = idx & 7;
    int rest = idx >> 3;
    int n = rest & 255;
    int b = rest >> 8;
    const float* pp = p1 + ((size_t)b * 256 + n) * 64;
    const float* qp = q + (size_t)b * 512 + m;
    float s = 0.f;
    for (int k = 0; k < 64; ++k) s += pp[k] * qp[(size_t)k * 8];
    outp[idx] = s;
}

// ---------------- host launch ----------------

extern "C" void kernel_launch(void* const* d_in, const int* in_sizes, int n_in,
                              void* d_out, int out_size, void* d_ws, size_t ws_size,
                              hipStream_t stream) {
    const float* pos    = (const float*)d_in[0];
    const float* ea     = (const float*)d_in[1];
    const int*   esrc   = (const int*)d_in[2];
    const int*   edst   = (const int*)d_in[3];
    const float* W1     = (const float*)d_in[4];
    const float* b1     = (const float*)d_in[5];
    const float* Wp1    = (const float*)d_in[6];
    const float* bp1    = (const float*)d_in[7];
    const float* Wrel2  = (const float*)d_in[8];
    const float* brel2  = (const float*)d_in[9];
    const float* Wroot2 = (const float*)d_in[10];
    const float* Wp2    = (const float*)d_in[11];
    const float* bp2    = (const float*)d_in[12];
    const float* Wrel3  = (const float*)d_in[13];
    const float* brel3  = (const float*)d_in[14];
    const float* Wroot3 = (const float*)d_in[15];
    const float* Wp3    = (const float*)d_in[16];
    const float* bp3    = (const float*)d_in[17];
    const float* Wrel4  = (const float*)d_in[18];
    const float* brel4  = (const float*)d_in[19];
    const float* Wroot4 = (const float*)d_in[20];
    float* out = (float*)d_out;

    char* w = (char*)d_ws;
    float* ADJ0 = (float*)w;                   // 16.7 MB unweighted adj (live thru L1)
    float* WADJ = (float*)(w + 16777216);      // 16.7 MB weighted adj (dead after zgemm)
    float* X    = (float*)(w + 33554432);      // 33.5 MB : y -> TMP
    char* sp    = w + 67108864;
    float* DINV   = (float*)(sp);
    float* XM     = (float*)(sp + 65536);      // L2/L3 means only (<=512 KB)
    float* DFLAT2 = (float*)(sp + 1114112);
    float* DFLAT3 = (float*)(sp + 1130496);
    float* P1     = (float*)(sp + 2162688);
    float* X1A    = (float*)(sp + 6356992);    // also Z overlay (Z dead before X1A write)
    float* OADJ1  = (float*)(sp + 14745600);
    float* P2     = (float*)(sp + 15794176);
    float* OADJ2  = (float*)(sp + 16318464);
    float* P3     = (float*)(sp + 16580608);
    float* X3A    = (float*)(sp + 16646144);
    float* OADJ3  = (float*)(sp + 17694720);
    float* DFLAT  = (float*)(sp + 17727488);
    float* P23    = (float*)(sp + 17793024);
    float* Z      = X1A;
    // overlays of the dead WADJ region (after zgemm):
    float* GBUF1 = (float*)(w + 16777216);             // NB*8192 floats = 2 MB
    float* GDEN1 = (float*)(w + 16777216 + 2097152);   // NB floats
    float* X1B   = (float*)(w + 16777216);             // written AFTER finish L1
    float* X2A   = (float*)(w + 25165824);
    float* GBUF2 = (float*)(w + 29360128);             // NB*2048 floats = 512 KB
    float* GDEN2 = (float*)(w + 29360128 + 524288);
    float* X2B   = (float*)(w + 29360128);             // written AFTER finish L2
    float* TMP   = X;                                  // valid after X's last read (L1 pool)
    float* MC    = out + 524288;                       // [mincut_total, ortho_total]

    hipMemsetAsync(ADJ0, 0, 33554432ull, stream);      // ADJ0 + WADJ
    hipMemsetAsync(MC, 0, 8, stream);                  // loss accumulators

    // GCN conv: deg -> weighted dense adj -> z = Wadj@pos -> fused y/mean/softmax
    k_init_deg<<<GRID(NNODES), 256, 0, stream>>>(DINV);
    k_edge_deg<<<GRID(NEDGES), 256, 0, stream>>>(edst, ea, DINV);
    k_rsqrt<<<GRID(NNODES), 256, 0, stream>>>(DINV);
    k_build<<<GRID(NEDGES), 256, 0, stream>>>(esrc, edst, ea, DINV, ADJ0, WADJ);
    k_zgemm<<<NB * 4, 256, 0, stream>>>(WADJ, pos, Z);
    // WADJ dead: zero the G scratch overlays
    hipMemsetAsync(GBUF1, 0, 2097152ull + 256, stream);
    hipMemsetAsync(GBUF2, 0, 524288ull + 256, stream);
    k_y2<<<NNODES, 512, 0, stream>>>(Z, pos, DINV, W1, b1, Wp1, bp1, X, P1);

    // ---- Level 1: Nc=256, Kc=64; x layout [N,T,H]: sb=131072, st=32, sn=512
    k_pool_t<256, 64, 128, 131072, 32, 512><<<NB * TC, 256, 0, stream>>>(P1, X, X1A);
    k_dflat<<<GRID(NB * 256), 256, 0, stream>>>(ADJ0, DFLAT, 256);
    k_adjp_t<256, 64, 128><<<NB * 8, 256, 0, stream>>>(ADJ0, P1, TMP);
    k_ssg<256, 64, 4, 4, 8><<<NB * 4, 256, 0, stream>>>(P1, TMP, DFLAT, GBUF1, GDEN1);
    k_finish<64, true><<<NB, 256, 0, stream>>>(GBUF1, GDEN1, OADJ1, DFLAT2, MC, MC + 1);
    k_graphconv_t<64, 32><<<NB * TC, 256, 0, stream>>>(OADJ1, X1A, Wrel2, brel2, Wroot2, X1B);

    // ---- Level 2: Nc=64, Kc=32; x1b layout [B,T,64,32]: sb=32768, st=2048, sn=32
    k_mean_t<<<GRID(NB * 64 * HC), 256, 0, stream>>>(X1B, XM, 64, 32768, 2048, 32);
    k_s_softmax<<<NB * 64, 64, 0, stream>>>(XM, Wp2, bp2, P2, 32);
    k_pool_t<64, 32, 64, 32768, 2048, 32><<<NB * TC, 256, 0, stream>>>(P2, X1B, X2A);
    k_adjp_t<64, 32, 64><<<NB * 2, 256, 0, stream>>>(OADJ1, P2, TMP);
    k_ssg<64, 32, 4, 2, 4><<<NB * 4, 256, 0, stream>>>(P2, TMP, DFLAT2, GBUF2, GDEN2);
    k_finish<32, true><<<NB, 256, 0, stream>>>(GBUF2, GDEN2, OADJ2, DFLAT3, MC, MC + 1);
    k_graphconv_t<32, 32><<<NB * TC, 256, 0, stream>>>(OADJ2, X2A, Wrel3, brel3, Wroot3, X2B);

    // ---- Level 3: Nc=32, Kc=8; x2b layout [B,T,32,32]: sb=16384, st=1024, sn=32
    k_mean_t<<<GRID(NB * 32 * HC), 256, 0, stream>>>(X2B, XM, 32, 16384, 1024, 32);
    k_s_softmax<<<NB * 32, 64, 0, stream>>>(XM, Wp3, bp3, P3, 8);
    k_pool_t<32, 8, 32, 16384, 1024, 32><<<NB * TC, 256, 0, stream>>>(P3, X2B, X3A);
    k_adjp_t<32, 8, 32><<<NB, 256, 0, stream>>>(OADJ2, P3, TMP);
    k_post_t<32, 8, 32, false><<<NB, 256, 0, stream>>>(P3, TMP, DFLAT3, OADJ3, DFLAT3, MC, MC + 1);
    k_graphconv_t<8, 64><<<NB * TC, 256, 0, stream>>>(OADJ3, X3A, Wrel4, brel4, Wroot4, out);

    // ---- agg = p1 @ (p2 @ p3)
    k_p23<<<GRID(NB * 64 * 8), 256, 0, stream>>>(P2, P3, P23);
    k_aggout<<<GRID(NB * 256 * 8), 256, 0, stream>>>(P1, P23, out + 524290);
}

// Round 6
// 306.631 us; speedup vs baseline: 1.2049x; 1.2049x over previous
//
#include <hip/hip_runtime.h>
#include <math.h>

#define NB 64
#define TC 16
#define HC 32
#define NNODES 16384
#define NEDGES 131072
#define EPSV 1e-15f

static inline int GRID(int n) { return (n + 255) / 256; }

template<int V> struct Log2 { static constexpr int v = 1 + Log2<V/2>::v; };
template<> struct Log2<1> { static constexpr int v = 0; };

// ---------------- GCN conv front-end ----------------

__global__ void k_init_deg(float* deg) {
    int i = blockIdx.x * 256 + threadIdx.x;
    if (i < NNODES) deg[i] = 1.0f;   // self-loop weight
}

__global__ void k_edge_deg(const int* __restrict__ dst, const float* __restrict__ ew,
                           float* __restrict__ deg) {
    int e = blockIdx.x * 256 + threadIdx.x;
    if (e < NEDGES) atomicAdd(&deg[dst[e]], ew[e]);
}

__global__ void k_rsqrt(float* deg) {
    int i = blockIdx.x * 256 + threadIdx.x;
    if (i < NNODES) { float d = deg[i]; deg[i] = (d > 0.f) ? rsqrtf(d) : 0.f; }
}

// fused: unweighted adj count (for mincut) + weighted adj coef (for GCN gather)
__global__ void k_build(const int* __restrict__ src, const int* __restrict__ dst,
                        const float* __restrict__ ew, const float* __restrict__ dinv,
                        float* __restrict__ adj, float* __restrict__ wadj) {
    int e = blockIdx.x * 256 + threadIdx.x;
    if (e >= NEDGES) return;
    int s = src[e], d = dst[e];
    int g = s >> 8, sl = s & 255, dl = d & 255;
    atomicAdd(&adj[((size_t)g << 16) + (sl << 8) + dl], 1.0f);
    float coef = dinv[s] * ew[e] * dinv[d];
    atomicAdd(&wadj[((size_t)g << 16) + (dl << 8) + sl], coef);
}

// z[b,d,0:48] = sum_s wadj[b,d,s] * pos[b,s,0:48]
__global__ void k_zgemm(const float* __restrict__ wadj, const float* __restrict__ pos,
                        float* __restrict__ z) {
    __shared__ __align__(16) float as_[64 * 36];
    __shared__ __align__(16) float bs[32 * 48];
    int b = blockIdx.x >> 2;
    int dtile = (blockIdx.x & 3) * 64;
    int tid = threadIdx.x;
    int d = tid >> 2, q = tid & 3;
    float acc[12];
#pragma unroll
    for (int j = 0; j < 12; ++j) acc[j] = 0.f;
    const float* arow = wadj + ((size_t)b << 16) + (size_t)dtile * 256;
    const float* pbase = pos + (size_t)b * 256 * 48;
    for (int s0 = 0; s0 < 256; s0 += 32) {
        for (int i = tid; i < 512; i += 256) {
            int r = i >> 3, c = i & 7;
            *(float4*)(as_ + r * 36 + c * 4) =
                *(const float4*)(arow + (size_t)r * 256 + s0 + c * 4);
        }
        for (int i = tid; i < 384; i += 256) {
            int r = i / 12, c = i % 12;
            *(float4*)(bs + r * 48 + c * 4) =
                *(const float4*)(pbase + (size_t)(s0 + r) * 48 + c * 4);
        }
        __syncthreads();
#pragma unroll 8
        for (int sp = 0; sp < 32; ++sp) {
            float a = as_[d * 36 + sp];
            const float* bp = &bs[sp * 48 + q * 12];
#pragma unroll
            for (int j = 0; j < 12; ++j) acc[j] += a * bp[j];
        }
        __syncthreads();
    }
    float* zr = z + (size_t)(b * 256 + dtile + d) * 48 + q * 12;
#pragma unroll
    for (int j = 0; j < 12; ++j) zr[j] = acc[j];
}

// Fused per-node: y = relu((z + pos*dinv^2)@W1 + b1)  [write X]
//                 xm = mean_t y ; s1 = tanh(xm@Wp1+bp1) ; p1 = softmax(s1)
__global__ __launch_bounds__(512) void k_y2(
        const float* __restrict__ z, const float* __restrict__ pos,
        const float* __restrict__ dinv, const float* __restrict__ W1,
        const float* __restrict__ b1, const float* __restrict__ Wp1,
        const float* __restrict__ bp1, float* __restrict__ y,
        float* __restrict__ p1) {
    __shared__ float ys[16][33];
    __shared__ __align__(16) float wp[32 * 64];
    __shared__ float xmv[32];
    int n = blockIdx.x;
    int tid = threadIdx.x;
    int t = tid >> 5, h = tid & 31;
    ((float4*)wp)[tid] = ((const float4*)Wp1)[tid];      // 512 float4 = 2048 floats
    const float* zr = z + (size_t)n * 48 + t * 3;
    const float* pr = pos + (size_t)n * 48 + t * 3;
    float di = dinv[n], d2 = di * di;
    float a0 = zr[0] + pr[0] * d2;
    float a1 = zr[1] + pr[1] * d2;
    float a2 = zr[2] + pr[2] * d2;
    float v = fmaxf(a0 * W1[h] + a1 * W1[32 + h] + a2 * W1[64 + h] + b1[h], 0.f);
    y[(size_t)n * 512 + tid] = v;
    ys[t][h] = v;
    __syncthreads();
    if (tid < 32) {
        float s = 0.f;
#pragma unroll
        for (int tt = 0; tt < 16; ++tt) s += ys[tt][tid];
        xmv[tid] = s * (1.0f / 16.0f);
    }
    __syncthreads();
    if (tid < 64) {
        float acc = bp1[tid];
#pragma unroll 8
        for (int hh = 0; hh < 32; ++hh) acc += xmv[hh] * wp[hh * 64 + tid];
        float vv = tanhf(acc);
        float m = vv;
        for (int o = 32; o > 0; o >>= 1) m = fmaxf(m, __shfl_xor(m, o));
        float e = expf(vv - m);
        float s = e;
        for (int o = 32; o > 0; o >>= 1) s += __shfl_xor(s, o);
        p1[(size_t)n * 64 + tid] = e / s;
    }
}

// ---------------- level kernels ----------------

// xm[r,h] = mean_t x[...]  (L2/L3 only)
__global__ void k_mean_t(const float* __restrict__ x, float* __restrict__ xm,
                         int Nc, int sb, int st, int sn) {
    int idx = blockIdx.x * 256 + threadIdx.x;
    int total = NB * Nc * HC;
    if (idx >= total) return;
    int h = idx & 31;
    int r = idx >> 5;
    int b = r / Nc, n = r % Nc;
    const float* p = x + (size_t)b * sb + (size_t)n * sn + h;
    float s = 0.f;
    for (int t = 0; t < TC; ++t) s += p[(size_t)t * st];
    xm[idx] = s * (1.0f / TC);
}

// one 64-lane wave per row: s = tanh(xm@Wp + bp), p = softmax_k(s)
__global__ void k_s_softmax(const float* __restrict__ xm, const float* __restrict__ Wp,
                            const float* __restrict__ bp, float* __restrict__ p, int Kc) {
    int r = blockIdx.x;
    int k = threadIdx.x;
    const float* xr = xm + (size_t)r * HC;
    float v = -1e30f;
    if (k < Kc) {
        float acc = bp[k];
        for (int h = 0; h < HC; ++h) acc += xr[h] * Wp[h * Kc + k];
        v = tanhf(acc);
    }
    float m = v;
    for (int o = 32; o > 0; o >>= 1) m = fmaxf(m, __shfl_xor(m, o));
    float e = (k < Kc) ? expf(v - m) : 0.f;
    float s = e;
    for (int o = 32; o > 0; o >>= 1) s += __shfl_xor(s, o);
    if (k < Kc) p[(size_t)r * Kc + k] = e / s;
}

// out[b,t,k,h] = sum_n p[(b*NC+n)*KC+k] * x[b*SB + t*STT + n*STN + h]
template<int NC, int KC, int NCH, int SB, int STT, int STN>
__global__ void k_pool_t(const float* __restrict__ p, const float* __restrict__ x,
                         float* __restrict__ outp) {
    constexpr int KPT = KC / 8;
    __shared__ __align__(16) float xs[NCH * HC];
    __shared__ __align__(16) float ps[NCH * KC];
    int bt = blockIdx.x;
    int b = bt >> 4, t = bt & 15;
    int tid = threadIdx.x;
    int h = tid & 31;
    int k0 = (tid >> 5) * KPT;
    float acc[KPT];
#pragma unroll
    for (int j = 0; j < KPT; ++j) acc[j] = 0.f;
    const float* xbase = x + (size_t)b * SB + (size_t)t * STT;
    const float* pbase = p + (size_t)b * NC * KC;
    for (int n0 = 0; n0 < NC; n0 += NCH) {
        for (int i = tid; i < NCH * 8; i += 256) {
            int n = i >> 3, q = i & 7;
            ((float4*)xs)[i] = ((const float4*)(xbase + (size_t)(n0 + n) * STN))[q];
        }
        for (int i = tid; i < NCH * KC / 4; i += 256)
            ((float4*)ps)[i] = ((const float4*)(pbase + (size_t)n0 * KC))[i];
        __syncthreads();
#pragma unroll 4
        for (int n = 0; n < NCH; ++n) {
            float xv = xs[n * HC + h];
#pragma unroll
            for (int j = 0; j < KPT; ++j) acc[j] += ps[n * KC + k0 + j] * xv;
        }
        __syncthreads();
    }
#pragma unroll
    for (int j = 0; j < KPT; ++j)
        outp[((size_t)bt * KC + k0 + j) * HC + h] = acc[j];
}

__global__ void k_dflat(const float* __restrict__ adj, float* __restrict__ dflat, int Nc) {
    int idx = blockIdx.x * 256 + threadIdx.x;
    if (idx >= NB * Nc) return;
    const float* a = adj + (size_t)idx * Nc;
    float s = 0.f;
    for (int m = 0; m < Nc; ++m) s += a[m];
    dflat[idx] = s;
}

// tmp[b,n,l] = sum_m adj[b,n,m]*p[b,m,l]; block per (b, 32-n tile), LDS staged
template<int NC, int KC, int MCH>
__global__ void k_adjp_t(const float* __restrict__ adj, const float* __restrict__ p,
                         float* __restrict__ tmp) {
    constexpr int LPT = KC / 8;
    constexpr int MROW = MCH + 4;
    constexpr int MQ = MCH / 4;
    constexpr int NBK = NC / 32;
    __shared__ __align__(16) float ps[MCH * KC];
    __shared__ __align__(16) float as_[32 * MROW];
    int b = blockIdx.x / NBK;
    int nt0 = (blockIdx.x % NBK) * 32;
    int tid = threadIdx.x;
    int n = tid >> 3;
    int l0 = (tid & 7) * LPT;
    float acc[LPT];
#pragma unroll
    for (int j = 0; j < LPT; ++j) acc[j] = 0.f;
    for (int m0 = 0; m0 < NC; m0 += MCH) {
        for (int i = tid; i < MCH * KC / 4; i += 256)
            ((float4*)ps)[i] = ((const float4*)(p + ((size_t)b * NC + m0) * KC))[i];
        for (int i = tid; i < 32 * MQ; i += 256) {
            int r = i / MQ, q = i % MQ;
            ((float4*)(as_ + r * MROW))[q] =
                ((const float4*)(adj + ((size_t)b * NC + nt0 + r) * NC + m0))[q];
        }
        __syncthreads();
#pragma unroll 4
        for (int m = 0; m < MCH; ++m) {
            float av = as_[n * MROW + m];
#pragma unroll
            for (int j = 0; j < LPT; ++j) acc[j] += av * ps[m * KC + l0 + j];
        }
        __syncthreads();
    }
#pragma unroll
    for (int j = 0; j < LPT; ++j)
        tmp[((size_t)b * NC + nt0 + n) * KC + l0 + j] = acc[j];
}

__device__ inline float blk_sum256(float v, float* rbuf) {
    for (int o = 32; o > 0; o >>= 1) v += __shfl_xor(v, o);
    __syncthreads();
    if ((threadIdx.x & 63) == 0) rbuf[threadIdx.x >> 6] = v;
    __syncthreads();
    return rbuf[0] + rbuf[1] + rbuf[2] + rbuf[3];
}

// Partial GEMM, NO atomics: G[split][b] = p_chunk^T @ [p_chunk | tmp_chunk] (plain
// stores), Gden[split*NB+b] = partial den. grid = NB * NSPLIT.
template<int NC, int KC, int NSPLIT, int KT, int LT>
__global__ void k_ssgp(const float* __restrict__ p, const float* __restrict__ tmp,
                       const float* __restrict__ dflat, float* __restrict__ G,
                       float* __restrict__ Gden) {
    constexpr int NCH = NC / NSPLIT;
    constexpr int LC = 2 * KC;
    constexpr int KQ = KC / 4;
    __shared__ __align__(16) float ab[NCH * LC];
    __shared__ float rbuf[4];
    int b = blockIdx.x / NSPLIT;
    int split = blockIdx.x % NSPLIT;
    int n0 = split * NCH;
    int tid = threadIdx.x;
    const float* pb = p + ((size_t)b * NC + n0) * KC;
    const float* tb = tmp + ((size_t)b * NC + n0) * KC;
    const float* db = dflat + (size_t)b * NC + n0;
    for (int i = tid; i < NCH * KQ; i += 256) {
        int r = i / KQ, c = i % KQ;
        *(float4*)(ab + r * LC + c * 4) = ((const float4*)pb)[i];
        *(float4*)(ab + r * LC + KC + c * 4) = ((const float4*)tb)[i];
    }
    __syncthreads();
    float den = 0.f;
    for (int i = tid; i < NCH * KQ; i += 256) {
        int r = i / KQ, c = i % KQ;
        float4 v = *(const float4*)(ab + r * LC + c * 4);
        den += (v.x * v.x + v.y * v.y + v.z * v.z + v.w * v.w) * db[r];
    }
    int kt = tid >> 4, lt = tid & 15;
    int k0 = kt * KT, l0 = lt * LT;
    float acc[KT][LT];
#pragma unroll
    for (int r = 0; r < KT; ++r)
#pragma unroll
        for (int c = 0; c < LT; ++c) acc[r][c] = 0.f;
#pragma unroll 4
    for (int n = 0; n < NCH; ++n) {
        float kv[KT], lv[LT];
#pragma unroll
        for (int r = 0; r < KT; ++r) kv[r] = ab[n * LC + k0 + r];
#pragma unroll
        for (int c = 0; c < LT; ++c) lv[c] = ab[n * LC + l0 + c];
#pragma unroll
        for (int r = 0; r < KT; ++r)
#pragma unroll
            for (int c = 0; c < LT; ++c) acc[r][c] += kv[r] * lv[c];
    }
    float* Gb = G + ((size_t)split * NB + b) * (KC * LC);
#pragma unroll
    for (int r = 0; r < KT; ++r)
#pragma unroll
        for (int c = 0; c < LT; ++c)
            Gb[(k0 + r) * LC + l0 + c] = acc[r][c];
    float dt = blk_sum256(den, rbuf);
    if (tid == 0) Gden[(size_t)split * NB + b] = dt;
}

// Per-batch finish: sum NSPLIT partials, losses, zero-diag+normalize, next dflat
template<int KC, int NSPLIT, bool DFN>
__global__ void k_finish(const float* __restrict__ G, const float* __restrict__ Gden,
                         float* __restrict__ oadj_out, float* __restrict__ dfn_out,
                         float* __restrict__ mc_out, float* __restrict__ or_out) {
    constexpr int LK = Log2<KC>::v;
    constexpr int KCP = KC + 1;
    constexpr int LC = 2 * KC;
    __shared__ float sss[KC * KCP];
    __shared__ float oss[KC * KCP];
    __shared__ float dvv[KC];
    __shared__ float rbuf[4];
    int b = blockIdx.x, tid = threadIdx.x;
    for (int i = tid; i < KC * KC; i += 256) {
        int k = i >> LK, l = i & (KC - 1);
        float sv = 0.f, ov = 0.f;
#pragma unroll
        for (int s = 0; s < NSPLIT; ++s) {
            const float* Gb = G + ((size_t)s * NB + b) * KC * LC;
            sv += Gb[k * LC + l];
            ov += Gb[k * LC + KC + l];
        }
        sss[k * KCP + l] = sv;
        oss[k * KCP + l] = ov;
    }
    __syncthreads();
    float ssn2 = 0.f;
    for (int i = tid; i < KC * KC; i += 256) {
        int k = i >> LK, l = i & (KC - 1);
        float v = sss[k * KCP + l];
        ssn2 += v * v;
    }
    float num = 0.f;
    for (int k = tid; k < KC; k += 256) num += oss[k * KCP + k];
    float ssn2_t = blk_sum256(ssn2, rbuf);
    float num_t = blk_sum256(num, rbuf);
    float den_t = 0.f;
#pragma unroll
    for (int s = 0; s < NSPLIT; ++s) den_t += Gden[(size_t)s * NB + b];
    float inv = 1.0f / sqrtf(ssn2_t);
    float dk = rsqrtf((float)KC);
    float o2 = 0.f;
    for (int i = tid; i < KC * KC; i += 256) {
        int k = i >> LK, l = i & (KC - 1);
        float v = sss[k * KCP + l] * inv - ((k == l) ? dk : 0.f);
        o2 += v * v;
    }
    float o2_t = blk_sum256(o2, rbuf);
    if (tid == 0) {
        atomicAdd(mc_out, -(num_t / den_t) * (1.0f / NB));
        atomicAdd(or_out, sqrtf(o2_t) * (1.0f / NB));
    }
    if (tid < KC) {
        float rs = 0.f;
        for (int l = 0; l < KC; ++l) rs += oss[tid * KCP + l];
        rs -= oss[tid * KCP + tid];
        dvv[tid] = sqrtf(rs) + EPSV;
    }
    __syncthreads();
    for (int i = tid; i < KC * KC; i += 256) {
        int k = i >> LK, l = i & (KC - 1);
        float v = (k == l) ? 0.f : oss[k * KCP + l] / (dvv[k] * dvv[l]);
        oadj_out[(size_t)b * KC * KC + i] = v;
    }
    if (DFN && tid < KC) {
        float s = 0.f;
        for (int l = 0; l < KC; ++l)
            if (l != tid) s += oss[tid * KCP + l] / (dvv[tid] * dvv[l]);
        dfn_out[(size_t)b * KC + tid] = s;
    }
}

// single-block post for tiny L3 (Nc=32, Kc=8)
template<int NC, int KC, int NCH, bool DFN>
__global__ void k_post_t(const float* __restrict__ p, const float* __restrict__ tmp,
                         const float* __restrict__ dflat, float* __restrict__ oadj_out,
                         float* __restrict__ dfn_out, float* __restrict__ mc_out,
                         float* __restrict__ or_out) {
    constexpr int LK = Log2<KC>::v;
    constexpr int KCP = KC + 1;
    constexpr int TW = KC / 4;
    constexpr int NT = TW * TW;
    __shared__ __align__(16) float ps[NCH * KC];
    __shared__ __align__(16) float ts[NCH * KC];
    __shared__ float sss[KC * KCP];
    __shared__ float oss[KC * KCP];
    __shared__ float dvv[KC];
    __shared__ float rbuf[4];
    int b = blockIdx.x, tid = threadIdx.x;
    const float* pb = p + (size_t)b * NC * KC;
    const float* tb = tmp + (size_t)b * NC * KC;
    const float* db = dflat + (size_t)b * NC;
    float sa[4][4], oa[4][4];
#pragma unroll
    for (int r = 0; r < 4; ++r)
#pragma unroll
        for (int c = 0; c < 4; ++c) { sa[r][c] = 0.f; oa[r][c] = 0.f; }
    int kt = (tid < NT) ? tid / TW : 0;
    int lt = (tid < NT) ? tid % TW : 0;
    float den = 0.f;
    for (int n0 = 0; n0 < NC; n0 += NCH) {
        for (int i = tid; i < NCH * KC / 4; i += 256) {
            ((float4*)ps)[i] = ((const float4*)(pb + (size_t)n0 * KC))[i];
            ((float4*)ts)[i] = ((const float4*)(tb + (size_t)n0 * KC))[i];
        }
        __syncthreads();
        for (int i4 = tid; i4 < NCH * KC / 4; i4 += 256) {
            float4 v = ((const float4*)ps)[i4];
            float dd = db[n0 + ((i4 * 4) >> LK)];
            den += (v.x * v.x + v.y * v.y + v.z * v.z + v.w * v.w) * dd;
        }
        if (tid < NT) {
#pragma unroll 4
            for (int nn = 0; nn < NCH; ++nn) {
                float4 kv4 = *(const float4*)&ps[nn * KC + kt * 4];
                float4 lv4 = *(const float4*)&ps[nn * KC + lt * 4];
                float4 tv4 = *(const float4*)&ts[nn * KC + lt * 4];
                float kv[4] = {kv4.x, kv4.y, kv4.z, kv4.w};
                float lv[4] = {lv4.x, lv4.y, lv4.z, lv4.w};
                float tv[4] = {tv4.x, tv4.y, tv4.z, tv4.w};
#pragma unroll
                for (int r = 0; r < 4; ++r)
#pragma unroll
                    for (int c = 0; c < 4; ++c) {
                        sa[r][c] += kv[r] * lv[c];
                        oa[r][c] += kv[r] * tv[c];
                    }
            }
        }
        __syncthreads();
    }
    if (tid < NT) {
#pragma unroll
        for (int r = 0; r < 4; ++r)
#pragma unroll
            for (int c = 0; c < 4; ++c) {
                sss[(kt * 4 + r) * KCP + lt * 4 + c] = sa[r][c];
                oss[(kt * 4 + r) * KCP + lt * 4 + c] = oa[r][c];
            }
    }
    __syncthreads();
    float ssn2 = 0.f;
    for (int i = tid; i < KC * KC; i += 256) {
        int k = i >> LK, l = i & (KC - 1);
        float v = sss[k * KCP + l];
        ssn2 += v * v;
    }
    float num = 0.f;
    for (int k = tid; k < KC; k += 256) num += oss[k * KCP + k];
    float den_t = blk_sum256(den, rbuf);
    float ssn2_t = blk_sum256(ssn2, rbuf);
    float num_t = blk_sum256(num, rbuf);
    float inv = 1.0f / sqrtf(ssn2_t);
    float dk = rsqrtf((float)KC);
    float o2 = 0.f;
    for (int i = tid; i < KC * KC; i += 256) {
        int k = i >> LK, l = i & (KC - 1);
        float v = sss[k * KCP + l] * inv - ((k == l) ? dk : 0.f);
        o2 += v * v;
    }
    float o2_t = blk_sum256(o2, rbuf);
    if (tid == 0) {
        atomicAdd(mc_out, -(num_t / den_t) * (1.0f / NB));
        atomicAdd(or_out, sqrtf(o2_t) * (1.0f / NB));
    }
    if (tid < KC) {
        float rs = 0.f;
        for (int l = 0; l < KC; ++l) rs += oss[tid * KCP + l];
        rs -= oss[tid * KCP + tid];
        dvv[tid] = sqrtf(rs) + EPSV;
    }
    __syncthreads();
    for (int i = tid; i < KC * KC; i += 256) {
        int k = i >> LK, l = i & (KC - 1);
        float v = (k == l) ? 0.f : oss[k * KCP + l] / (dvv[k] * dvv[l]);
        oadj_out[(size_t)b * KC * KC + i] = v;
    }
    if (DFN && tid < KC) {
        float s = 0.f;
        for (int l = 0; l < KC; ++l)
            if (l != tid) s += oss[tid * KCP + l] / (dvv[tid] * dvv[l]);
        dfn_out[(size_t)b * KC + tid] = s;
    }
}

// Fused dense_graph_conv per (b,t): out = (adjn@x)@Wrel + brel + x@Wroot
template<int NC2, int OC>
__global__ void k_graphconv_t(const float* __restrict__ adjn, const float* __restrict__ x,
                              const float* __restrict__ Wrel, const float* __restrict__ brel,
                              const float* __restrict__ Wroot, float* __restrict__ outp) {
    constexpr int EL1 = NC2 * HC / 256;
    constexpr int EL2 = NC2 * OC / 256;
    constexpr int LOC = Log2<OC>::v;
    __shared__ __align__(16) float xs[NC2 * HC];
    __shared__ __align__(16) float as_[NC2 * NC2];
    __shared__ float c1[NC2 * HC];
    int bt = blockIdx.x;
    int b = bt >> 4;
    int tid = threadIdx.x;
    for (int i = tid; i < NC2 * HC / 4; i += 256)
        ((float4*)xs)[i] = ((const float4*)(x + (size_t)bt * NC2 * HC))[i];
    for (int i = tid; i < NC2 * NC2 / 4; i += 256)
        ((float4*)as_)[i] = ((const float4*)(adjn + (size_t)b * NC2 * NC2))[i];
    __syncthreads();
#pragma unroll
    for (int e = 0; e < EL1; ++e) {
        int idx = tid + e * 256;
        int hh = idx & 31, n = idx >> 5;
        float acc = 0.f;
#pragma unroll 8
        for (int m = 0; m < NC2; ++m) acc += as_[n * NC2 + m] * xs[m * HC + hh];
        c1[idx] = acc;
    }
    __syncthreads();
#pragma unroll
    for (int e = 0; e < EL2; ++e) {
        int idx = tid + e * 256;
        int o = idx & (OC - 1), n = idx >> LOC;
        float acc = brel[o];
#pragma unroll 8
        for (int hh = 0; hh < HC; ++hh)
            acc += c1[n * HC + hh] * Wrel[hh * OC + o] + xs[n * HC + hh] * Wroot[hh * OC + o];
        outp[(size_t)bt * NC2 * OC + idx] = acc;
    }
}

// q[b,k,m] = sum_l p2[b,k,l] * p3[b,l,m]
__global__ void k_p23(const float* __restrict__ p2, const float* __restrict__ p3,
                      float* __restrict__ q) {
    int idx = blockIdx.x * 256 + threadIdx.x;
    if (idx >= NB * 64 * 8) return;
    int m = idx & 7;
    int rest = idx >> 3;
    int k = rest % 64;
    int b = rest / 64;
    const float* p2p = p2 + ((size_t)b * 64 + k) * 32;
    const float* p3p = p3 + (size_t)b * 32 * 8 + m;
    float s = 0.f;
    for (int l = 0; l < 32; ++l) s += p2p[l] * p3p[(size_t)l * 8];
    q[idx] = s;
}

// aggout[b,n,m] = sum_k p1[b,n,k] * q[b,k,m]
__global__ void k_aggout(const float* __restrict__ p1, const float* __restrict__ q,
                         float* __restrict__ outp) {
    int idx = blockIdx.x * 256 + threadIdx.x;
    if (idx >= NB * 256 * 8) return;
    int m = idx & 7;
    int rest = idx >> 3;
    int n = rest & 255;
    int b = rest >> 8;
    const float* pp = p1 + ((size_t)b * 256 + n) * 64;
    const float* qp = q + (size_t)b * 512 + m;
    float s = 0.f;
    for (int k = 0; k < 64; ++k) s += pp[k] * qp[(size_t)k * 8];
    outp[idx] = s;
}

// ---------------- host launch ----------------

extern "C" void kernel_launch(void* const* d_in, const int* in_sizes, int n_in,
                              void* d_out, int out_size, void* d_ws, size_t ws_size,
                              hipStream_t stream) {
    const float* pos    = (const float*)d_in[0];
    const float* ea     = (const float*)d_in[1];
    const int*   esrc   = (const int*)d_in[2];
    const int*   edst   = (const int*)d_in[3];
    const float* W1     = (const float*)d_in[4];
    const float* b1     = (const float*)d_in[5];
    const float* Wp1    = (const float*)d_in[6];
    const float* bp1    = (const float*)d_in[7];
    const float* Wrel2  = (const float*)d_in[8];
    const float* brel2  = (const float*)d_in[9];
    const float* Wroot2 = (const float*)d_in[10];
    const float* Wp2    = (const float*)d_in[11];
    const float* bp2    = (const float*)d_in[12];
    const float* Wrel3  = (const float*)d_in[13];
    const float* brel3  = (const float*)d_in[14];
    const float* Wroot3 = (const float*)d_in[15];
    const float* Wp3    = (const float*)d_in[16];
    const float* bp3    = (const float*)d_in[17];
    const float* Wrel4  = (const float*)d_in[18];
    const float* brel4  = (const float*)d_in[19];
    const float* Wroot4 = (const float*)d_in[20];
    float* out = (float*)d_out;

    char* w = (char*)d_ws;
    float* ADJ0 = (float*)w;                   // 16.7 MB unweighted adj (live thru L1)
    float* WADJ = (float*)(w + 16777216);      // 16.7 MB weighted adj (dead after zgemm)
    float* X    = (float*)(w + 33554432);      // 33.5 MB : y -> TMP
    char* sp    = w + 67108864;
    float* DINV   = (float*)(sp);
    float* XM     = (float*)(sp + 65536);      // L2/L3 means only (<=512 KB)
    float* DFLAT2 = (float*)(sp + 1114112);
    float* DFLAT3 = (float*)(sp + 1130496);
    float* GDEN1  = (float*)(sp + 1146880);    // 4*64 floats
    float* GDEN2  = (float*)(sp + 1150976);    // 4*64 floats
    float* P1     = (float*)(sp + 2162688);
    float* X1A    = (float*)(sp + 6356992);    // also Z overlay (Z dead before X1A write)
    float* OADJ1  = (float*)(sp + 14745600);
    float* P2     = (float*)(sp + 15794176);
    float* OADJ2  = (float*)(sp + 16318464);
    float* P3     = (float*)(sp + 16580608);
    float* X3A    = (float*)(sp + 16646144);
    float* OADJ3  = (float*)(sp + 17694720);
    float* DFLAT  = (float*)(sp + 17727488);
    float* P23    = (float*)(sp + 17793024);
    float* Z      = X1A;
    // overlays of the dead WADJ region (after zgemm):
    float* GBUF1 = (float*)(w + 16777216);             // 4 splits * 64 b * 8192 = 8 MB
    float* X1B   = (float*)(w + 16777216);             // written AFTER finish L1
    float* X2A   = (float*)(w + 25165824);
    float* GBUF2 = (float*)(w + 29360128);             // 4 * 64 * 2048 = 2 MB
    float* X2B   = (float*)(w + 29360128);             // written AFTER finish L2
    float* TMP   = X;                                  // valid after X's last read (L1 pool)
    float* MC    = out + 524288;                       // [mincut_total, ortho_total]

    hipMemsetAsync(ADJ0, 0, 33554432ull, stream);      // ADJ0 + WADJ
    hipMemsetAsync(MC, 0, 8, stream);                  // loss accumulators

    // GCN conv: deg -> weighted dense adj -> z = Wadj@pos -> fused y/mean/softmax
    k_init_deg<<<GRID(NNODES), 256, 0, stream>>>(DINV);
    k_edge_deg<<<GRID(NEDGES), 256, 0, stream>>>(edst, ea, DINV);
    k_rsqrt<<<GRID(NNODES), 256, 0, stream>>>(DINV);
    k_build<<<GRID(NEDGES), 256, 0, stream>>>(esrc, edst, ea, DINV, ADJ0, WADJ);
    k_zgemm<<<NB * 4, 256, 0, stream>>>(WADJ, pos, Z);
    k_y2<<<NNODES, 512, 0, stream>>>(Z, pos, DINV, W1, b1, Wp1, bp1, X, P1);

    // ---- Level 1: Nc=256, Kc=64; x layout [N,T,H]: sb=131072, st=32, sn=512
    k_pool_t<256, 64, 128, 131072, 32, 512><<<NB * TC, 256, 0, stream>>>(P1, X, X1A);
    k_dflat<<<GRID(NB * 256), 256, 0, stream>>>(ADJ0, DFLAT, 256);
    k_adjp_t<256, 64, 128><<<NB * 8, 256, 0, stream>>>(ADJ0, P1, TMP);
    k_ssgp<256, 64, 4, 4, 8><<<NB * 4, 256, 0, stream>>>(P1, TMP, DFLAT, GBUF1, GDEN1);
    k_finish<64, 4, true><<<NB, 256, 0, stream>>>(GBUF1, GDEN1, OADJ1, DFLAT2, MC, MC + 1);
    k_graphconv_t<64, 32><<<NB * TC, 256, 0, stream>>>(OADJ1, X1A, Wrel2, brel2, Wroot2, X1B);

    // ---- Level 2: Nc=64, Kc=32; x1b layout [B,T,64,32]: sb=32768, st=2048, sn=32
    k_mean_t<<<GRID(NB * 64 * HC), 256, 0, stream>>>(X1B, XM, 64, 32768, 2048, 32);
    k_s_softmax<<<NB * 64, 64, 0, stream>>>(XM, Wp2, bp2, P2, 32);
    k_pool_t<64, 32, 64, 32768, 2048, 32><<<NB * TC, 256, 0, stream>>>(P2, X1B, X2A);
    k_adjp_t<64, 32, 64><<<NB * 2, 256, 0, stream>>>(OADJ1, P2, TMP);
    k_ssgp<64, 32, 4, 2, 4><<<NB * 4, 256, 0, stream>>>(P2, TMP, DFLAT2, GBUF2, GDEN2);
    k_finish<32, 4, true><<<NB, 256, 0, stream>>>(GBUF2, GDEN2, OADJ2, DFLAT3, MC, MC + 1);
    k_graphconv_t<32, 32><<<NB * TC, 256, 0, stream>>>(OADJ2, X2A, Wrel3, brel3, Wroot3, X2B);

    // ---- Level 3: Nc=32, Kc=8; x2b layout [B,T,32,32]: sb=16384, st=1024, sn=32
    k_mean_t<<<GRID(NB * 32 * HC), 256, 0, stream>>>(X2B, XM, 32, 16384, 1024, 32);
    k_s_softmax<<<NB * 32, 64, 0, stream>>>(XM, Wp3, bp3, P3, 8);
    k_pool_t<32, 8, 32, 16384, 1024, 32><<<NB * TC, 256, 0, stream>>>(P3, X2B, X3A);
    k_adjp_t<32, 8, 32><<<NB, 256, 0, stream>>>(OADJ2, P3, TMP);
    k_post_t<32, 8, 32, false><<<NB, 256, 0, stream>>>(P3, TMP, DFLAT3, OADJ3, DFLAT3, MC, MC + 1);
    k_graphconv_t<8, 64><<<NB * TC, 256, 0, stream>>>(OADJ3, X3A, Wrel4, brel4, Wroot4, out);

    // ---- agg = p1 @ (p2 @ p3)
    k_p23<<<GRID(NB * 64 * 8), 256, 0, stream>>>(P2, P3, P23);
    k_aggout<<<GRID(NB * 256 * 8), 256, 0, stream>>>(P1, P23, out + 524290);
}

// Round 7
// 266.798 us; speedup vs baseline: 1.3848x; 1.1493x over previous
//
#include <hip/hip_runtime.h>
#include <math.h>

#define NB 64
#define TC 16
#define HC 32
#define NNODES 16384
#define NEDGES 131072
#define EPSV 1e-15f

static inline int GRID(int n) { return (n + 255) / 256; }

template<int V> struct Log2 { static constexpr int v = 1 + Log2<V/2>::v; };
template<> struct Log2<1> { static constexpr int v = 0; };

// ---------------- utility ----------------

__global__ void k_zero(float4* __restrict__ dst, int n4) {
    int i = blockIdx.x * 256 + threadIdx.x;
    int stride = gridDim.x * 256;
    for (; i < n4; i += stride) dst[i] = make_float4(0.f, 0.f, 0.f, 0.f);
}

// ---------------- GCN conv front-end ----------------

__global__ void k_init_deg(float* deg, float* mc) {
    int i = blockIdx.x * 256 + threadIdx.x;
    if (i < NNODES) deg[i] = 1.0f;   // self-loop weight
    if (i < 2) mc[i] = 0.f;          // loss accumulators
}

__global__ void k_edge_deg(const int* __restrict__ dst, const float* __restrict__ ew,
                           float* __restrict__ deg) {
    int e = blockIdx.x * 256 + threadIdx.x;
    if (e < NEDGES) atomicAdd(&deg[dst[e]], ew[e]);
}

__global__ void k_rsqrt(float* deg) {
    int i = blockIdx.x * 256 + threadIdx.x;
    if (i < NNODES) { float d = deg[i]; deg[i] = (d > 0.f) ? rsqrtf(d) : 0.f; }
}

// fused: unweighted adj count (for mincut) + weighted adj coef (for GCN gather)
__global__ void k_build(const int* __restrict__ src, const int* __restrict__ dst,
                        const float* __restrict__ ew, const float* __restrict__ dinv,
                        float* __restrict__ adj, float* __restrict__ wadj) {
    int e = blockIdx.x * 256 + threadIdx.x;
    if (e >= NEDGES) return;
    int s = src[e], d = dst[e];
    int g = s >> 8, sl = s & 255, dl = d & 255;
    atomicAdd(&adj[((size_t)g << 16) + (sl << 8) + dl], 1.0f);
    float coef = dinv[s] * ew[e] * dinv[d];
    atomicAdd(&wadj[((size_t)g << 16) + (dl << 8) + sl], coef);
}

// z[b,d,0:48] = sum_s wadj[b,d,s] * pos[b,s,0:48]
__global__ void k_zgemm(const float* __restrict__ wadj, const float* __restrict__ pos,
                        float* __restrict__ z) {
    __shared__ __align__(16) float as_[64 * 36];
    __shared__ __align__(16) float bs[32 * 48];
    int b = blockIdx.x >> 2;
    int dtile = (blockIdx.x & 3) * 64;
    int tid = threadIdx.x;
    int d = tid >> 2, q = tid & 3;
    float acc[12];
#pragma unroll
    for (int j = 0; j < 12; ++j) acc[j] = 0.f;
    const float* arow = wadj + ((size_t)b << 16) + (size_t)dtile * 256;
    const float* pbase = pos + (size_t)b * 256 * 48;
    for (int s0 = 0; s0 < 256; s0 += 32) {
        for (int i = tid; i < 512; i += 256) {
            int r = i >> 3, c = i & 7;
            *(float4*)(as_ + r * 36 + c * 4) =
                *(const float4*)(arow + (size_t)r * 256 + s0 + c * 4);
        }
        for (int i = tid; i < 384; i += 256) {
            int r = i / 12, c = i % 12;
            *(float4*)(bs + r * 48 + c * 4) =
                *(const float4*)(pbase + (size_t)(s0 + r) * 48 + c * 4);
        }
        __syncthreads();
#pragma unroll 8
        for (int sp = 0; sp < 32; ++sp) {
            float a = as_[d * 36 + sp];
            const float* bp = &bs[sp * 48 + q * 12];
#pragma unroll
            for (int j = 0; j < 12; ++j) acc[j] += a * bp[j];
        }
        __syncthreads();
    }
    float* zr = z + (size_t)(b * 256 + dtile + d) * 48 + q * 12;
#pragma unroll
    for (int j = 0; j < 12; ++j) zr[j] = acc[j];
}

// Fused per-node: y = relu((z + pos*dinv^2)@W1 + b1)  [write X]
//                 xm = mean_t y ; s1 = tanh(xm@Wp1+bp1) ; p1 = softmax(s1)
__global__ __launch_bounds__(512) void k_y2(
        const float* __restrict__ z, const float* __restrict__ pos,
        const float* __restrict__ dinv, const float* __restrict__ W1,
        const float* __restrict__ b1, const float* __restrict__ Wp1,
        const float* __restrict__ bp1, float* __restrict__ y,
        float* __restrict__ p1) {
    __shared__ float ys[16][33];
    __shared__ __align__(16) float wp[32 * 64];
    __shared__ float xmv[32];
    int n = blockIdx.x;
    int tid = threadIdx.x;
    int t = tid >> 5, h = tid & 31;
    ((float4*)wp)[tid] = ((const float4*)Wp1)[tid];      // 512 float4 = 2048 floats
    const float* zr = z + (size_t)n * 48 + t * 3;
    const float* pr = pos + (size_t)n * 48 + t * 3;
    float di = dinv[n], d2 = di * di;
    float a0 = zr[0] + pr[0] * d2;
    float a1 = zr[1] + pr[1] * d2;
    float a2 = zr[2] + pr[2] * d2;
    float v = fmaxf(a0 * W1[h] + a1 * W1[32 + h] + a2 * W1[64 + h] + b1[h], 0.f);
    y[(size_t)n * 512 + tid] = v;
    ys[t][h] = v;
    __syncthreads();
    if (tid < 32) {
        float s = 0.f;
#pragma unroll
        for (int tt = 0; tt < 16; ++tt) s += ys[tt][tid];
        xmv[tid] = s * (1.0f / 16.0f);
    }
    __syncthreads();
    if (tid < 64) {
        float acc = bp1[tid];
#pragma unroll 8
        for (int hh = 0; hh < 32; ++hh) acc += xmv[hh] * wp[hh * 64 + tid];
        float vv = tanhf(acc);
        float m = vv;
        for (int o = 32; o > 0; o >>= 1) m = fmaxf(m, __shfl_xor(m, o));
        float e = expf(vv - m);
        float s = e;
        for (int o = 32; o > 0; o >>= 1) s += __shfl_xor(s, o);
        p1[(size_t)n * 64 + tid] = e / s;
    }
}

// ---------------- level kernels ----------------

// xm[r,h] = mean_t x[...]  (L2/L3 only)
__global__ void k_mean_t(const float* __restrict__ x, float* __restrict__ xm,
                         int Nc, int sb, int st, int sn) {
    int idx = blockIdx.x * 256 + threadIdx.x;
    int total = NB * Nc * HC;
    if (idx >= total) return;
    int h = idx & 31;
    int r = idx >> 5;
    int b = r / Nc, n = r % Nc;
    const float* p = x + (size_t)b * sb + (size_t)n * sn + h;
    float s = 0.f;
    for (int t = 0; t < TC; ++t) s += p[(size_t)t * st];
    xm[idx] = s * (1.0f / TC);
}

// one 64-lane wave per row: s = tanh(xm@Wp + bp), p = softmax_k(s)
__global__ void k_s_softmax(const float* __restrict__ xm, const float* __restrict__ Wp,
                            const float* __restrict__ bp, float* __restrict__ p, int Kc) {
    int r = blockIdx.x;
    int k = threadIdx.x;
    const float* xr = xm + (size_t)r * HC;
    float v = -1e30f;
    if (k < Kc) {
        float acc = bp[k];
        for (int h = 0; h < HC; ++h) acc += xr[h] * Wp[h * Kc + k];
        v = tanhf(acc);
    }
    float m = v;
    for (int o = 32; o > 0; o >>= 1) m = fmaxf(m, __shfl_xor(m, o));
    float e = (k < Kc) ? expf(v - m) : 0.f;
    float s = e;
    for (int o = 32; o > 0; o >>= 1) s += __shfl_xor(s, o);
    if (k < Kc) p[(size_t)r * Kc + k] = e / s;
}

// out[b,t,k,h] = sum_n p[(b*NC+n)*KC+k] * x[b*SB + t*STT + n*STN + h]
// register-tiled: each thread owns 4k x 4h; 2 ds_read_b128 per 16 FMA.
template<int NC, int KC, int NCH, int SB, int STT, int STN>
__global__ void k_pool4(const float* __restrict__ p, const float* __restrict__ x,
                        float* __restrict__ outp) {
    constexpr int TPT = KC * 2;           // threads per t: (KC/4) * 8
    constexpr int TPB = 256 / TPT;        // t's per block
    constexpr int NTILE = TC / TPB;       // blocks per batch
    __shared__ __align__(16) float ps[NCH * KC];
    __shared__ __align__(16) float xs[TPB * NCH * HC];
    int b = blockIdx.x / NTILE;
    int t0 = (blockIdx.x % NTILE) * TPB;
    int tid = threadIdx.x;
    int th = tid / TPT;
    int r = tid % TPT;
    int k0 = (r >> 3) * 4;
    int h0 = (r & 7) * 4;
    float acc[4][4];
#pragma unroll
    for (int rr = 0; rr < 4; ++rr)
#pragma unroll
        for (int cc = 0; cc < 4; ++cc) acc[rr][cc] = 0.f;
    const float* pbase = p + (size_t)b * NC * KC;
    const float* xbase = x + (size_t)b * SB + (size_t)t0 * STT;
    for (int n0 = 0; n0 < NC; n0 += NCH) {
        for (int i = tid; i < NCH * KC / 4; i += 256)
            ((float4*)ps)[i] = ((const float4*)(pbase + (size_t)n0 * KC))[i];
        for (int i = tid; i < TPB * NCH * 8; i += 256) {
            int q = i & 7;
            int n = (i >> 3) % NCH;
            int tt = i / (NCH * 8);
            *(float4*)&xs[(tt * NCH + n) * HC + q * 4] =
                *(const float4*)(xbase + (size_t)tt * STT + (size_t)(n0 + n) * STN + q * 4);
        }
        __syncthreads();
#pragma unroll 4
        for (int n = 0; n < NCH; ++n) {
            float4 kv4 = *(const float4*)&ps[n * KC + k0];
            float4 xv4 = *(const float4*)&xs[(th * NCH + n) * HC + h0];
            float kv[4] = {kv4.x, kv4.y, kv4.z, kv4.w};
            float xv[4] = {xv4.x, xv4.y, xv4.z, xv4.w};
#pragma unroll
            for (int rr = 0; rr < 4; ++rr)
#pragma unroll
                for (int cc = 0; cc < 4; ++cc) acc[rr][cc] += kv[rr] * xv[cc];
        }
        __syncthreads();
    }
    float* ob = outp + (((size_t)(b * TC + t0 + th) * KC + k0) * HC + h0);
#pragma unroll
    for (int rr = 0; rr < 4; ++rr) {
        float4 v = {acc[rr][0], acc[rr][1], acc[rr][2], acc[rr][3]};
        *(float4*)(ob + (size_t)rr * HC) = v;
    }
}

// tmp[b,n,l] = sum_m adj[b,n,m]*p[b,m,l]; block per (b, 32-n tile), LDS staged.
// DF: also emit dflat row sums (each thread already reads the full adj row).
template<int NC, int KC, int MCH, bool DF>
__global__ void k_adjp_t(const float* __restrict__ adj, const float* __restrict__ p,
                         float* __restrict__ tmp, float* __restrict__ dflat) {
    constexpr int LPT = KC / 8;
    constexpr int MROW = MCH + 4;
    constexpr int MQ = MCH / 4;
    constexpr int NBK = NC / 32;
    __shared__ __align__(16) float ps[MCH * KC];
    __shared__ __align__(16) float as_[32 * MROW];
    int b = blockIdx.x / NBK;
    int nt0 = (blockIdx.x % NBK) * 32;
    int tid = threadIdx.x;
    int n = tid >> 3;
    int l0 = (tid & 7) * LPT;
    float acc[LPT];
#pragma unroll
    for (int j = 0; j < LPT; ++j) acc[j] = 0.f;
    float rs = 0.f;
    for (int m0 = 0; m0 < NC; m0 += MCH) {
        for (int i = tid; i < MCH * KC / 4; i += 256)
            ((float4*)ps)[i] = ((const float4*)(p + ((size_t)b * NC + m0) * KC))[i];
        for (int i = tid; i < 32 * MQ; i += 256) {
            int r = i / MQ, q = i % MQ;
            ((float4*)(as_ + r * MROW))[q] =
                ((const float4*)(adj + ((size_t)b * NC + nt0 + r) * NC + m0))[q];
        }
        __syncthreads();
#pragma unroll 4
        for (int m = 0; m < MCH; ++m) {
            float av = as_[n * MROW + m];
            rs += av;
#pragma unroll
            for (int j = 0; j < LPT; ++j) acc[j] += av * ps[m * KC + l0 + j];
        }
        __syncthreads();
    }
#pragma unroll
    for (int j = 0; j < LPT; ++j)
        tmp[((size_t)b * NC + nt0 + n) * KC + l0 + j] = acc[j];
    if (DF && (tid & 7) == 0)
        dflat[(size_t)b * NC + nt0 + n] = rs;
}

__device__ inline float blk_sum256(float v, float* rbuf) {
    for (int o = 32; o > 0; o >>= 1) v += __shfl_xor(v, o);
    __syncthreads();
    if ((threadIdx.x & 63) == 0) rbuf[threadIdx.x >> 6] = v;
    __syncthreads();
    return rbuf[0] + rbuf[1] + rbuf[2] + rbuf[3];
}

// Partial GEMM, NO atomics: G[split][b] = p_chunk^T @ [p_chunk | tmp_chunk] (plain
// stores), Gden[split*NB+b] = partial den. grid = NB * NSPLIT.
template<int NC, int KC, int NSPLIT, int KT, int LT>
__global__ void k_ssgp(const float* __restrict__ p, const float* __restrict__ tmp,
                       const float* __restrict__ dflat, float* __restrict__ G,
                       float* __restrict__ Gden) {
    constexpr int NCH = NC / NSPLIT;
    constexpr int LC = 2 * KC;
    constexpr int KQ = KC / 4;
    __shared__ __align__(16) float ab[NCH * LC];
    __shared__ float rbuf[4];
    int b = blockIdx.x / NSPLIT;
    int split = blockIdx.x % NSPLIT;
    int n0 = split * NCH;
    int tid = threadIdx.x;
    const float* pb = p + ((size_t)b * NC + n0) * KC;
    const float* tb = tmp + ((size_t)b * NC + n0) * KC;
    const float* db = dflat + (size_t)b * NC + n0;
    for (int i = tid; i < NCH * KQ; i += 256) {
        int r = i / KQ, c = i % KQ;
        *(float4*)(ab + r * LC + c * 4) = ((const float4*)pb)[i];
        *(float4*)(ab + r * LC + KC + c * 4) = ((const float4*)tb)[i];
    }
    __syncthreads();
    float den = 0.f;
    for (int i = tid; i < NCH * KQ; i += 256) {
        int r = i / KQ, c = i % KQ;
        float4 v = *(const float4*)(ab + r * LC + c * 4);
        den += (v.x * v.x + v.y * v.y + v.z * v.z + v.w * v.w) * db[r];
    }
    int kt = tid >> 4, lt = tid & 15;
    int k0 = kt * KT, l0 = lt * LT;
    float acc[KT][LT];
#pragma unroll
    for (int r = 0; r < KT; ++r)
#pragma unroll
        for (int c = 0; c < LT; ++c) acc[r][c] = 0.f;
#pragma unroll 4
    for (int n = 0; n < NCH; ++n) {
        float kv[KT], lv[LT];
#pragma unroll
        for (int r = 0; r < KT; ++r) kv[r] = ab[n * LC + k0 + r];
#pragma unroll
        for (int c = 0; c < LT; ++c) lv[c] = ab[n * LC + l0 + c];
#pragma unroll
        for (int r = 0; r < KT; ++r)
#pragma unroll
            for (int c = 0; c < LT; ++c) acc[r][c] += kv[r] * lv[c];
    }
    float* Gb = G + ((size_t)split * NB + b) * (KC * LC);
#pragma unroll
    for (int r = 0; r < KT; ++r)
#pragma unroll
        for (int c = 0; c < LT; ++c)
            Gb[(k0 + r) * LC + l0 + c] = acc[r][c];
    float dt = blk_sum256(den, rbuf);
    if (tid == 0) Gden[(size_t)split * NB + b] = dt;
}

// Per-batch finish: sum NSPLIT partials, losses, zero-diag+normalize, next dflat
template<int KC, int NSPLIT, bool DFN>
__global__ void k_finish(const float* __restrict__ G, const float* __restrict__ Gden,
                         float* __restrict__ oadj_out, float* __restrict__ dfn_out,
                         float* __restrict__ mc_out, float* __restrict__ or_out) {
    constexpr int LK = Log2<KC>::v;
    constexpr int KCP = KC + 1;
    constexpr int LC = 2 * KC;
    __shared__ float sss[KC * KCP];
    __shared__ float oss[KC * KCP];
    __shared__ float dvv[KC];
    __shared__ float rbuf[4];
    int b = blockIdx.x, tid = threadIdx.x;
    for (int i = tid; i < KC * KC; i += 256) {
        int k = i >> LK, l = i & (KC - 1);
        float sv = 0.f, ov = 0.f;
#pragma unroll
        for (int s = 0; s < NSPLIT; ++s) {
            const float* Gb = G + ((size_t)s * NB + b) * KC * LC;
            sv += Gb[k * LC + l];
            ov += Gb[k * LC + KC + l];
        }
        sss[k * KCP + l] = sv;
        oss[k * KCP + l] = ov;
    }
    __syncthreads();
    float ssn2 = 0.f;
    for (int i = tid; i < KC * KC; i += 256) {
        int k = i >> LK, l = i & (KC - 1);
        float v = sss[k * KCP + l];
        ssn2 += v * v;
    }
    float num = 0.f;
    for (int k = tid; k < KC; k += 256) num += oss[k * KCP + k];
    float ssn2_t = blk_sum256(ssn2, rbuf);
    float num_t = blk_sum256(num, rbuf);
    float den_t = 0.f;
#pragma unroll
    for (int s = 0; s < NSPLIT; ++s) den_t += Gden[(size_t)s * NB + b];
    float inv = 1.0f / sqrtf(ssn2_t);
    float dk = rsqrtf((float)KC);
    float o2 = 0.f;
    for (int i = tid; i < KC * KC; i += 256) {
        int k = i >> LK, l = i & (KC - 1);
        float v = sss[k * KCP + l] * inv - ((k == l) ? dk : 0.f);
        o2 += v * v;
    }
    float o2_t = blk_sum256(o2, rbuf);
    if (tid == 0) {
        atomicAdd(mc_out, -(num_t / den_t) * (1.0f / NB));
        atomicAdd(or_out, sqrtf(o2_t) * (1.0f / NB));
    }
    if (tid < KC) {
        float rs = 0.f;
        for (int l = 0; l < KC; ++l) rs += oss[tid * KCP + l];
        rs -= oss[tid * KCP + tid];
        dvv[tid] = sqrtf(rs) + EPSV;
    }
    __syncthreads();
    for (int i = tid; i < KC * KC; i += 256) {
        int k = i >> LK, l = i & (KC - 1);
        float v = (k == l) ? 0.f : oss[k * KCP + l] / (dvv[k] * dvv[l]);
        oadj_out[(size_t)b * KC * KC + i] = v;
    }
    if (DFN && tid < KC) {
        float s = 0.f;
        for (int l = 0; l < KC; ++l)
            if (l != tid) s += oss[tid * KCP + l] / (dvv[tid] * dvv[l]);
        dfn_out[(size_t)b * KC + tid] = s;
    }
}

// single-block post for tiny L3 (Nc=32, Kc=8)
template<int NC, int KC, int NCH, bool DFN>
__global__ void k_post_t(const float* __restrict__ p, const float* __restrict__ tmp,
                         const float* __restrict__ dflat, float* __restrict__ oadj_out,
                         float* __restrict__ dfn_out, float* __restrict__ mc_out,
                         float* __restrict__ or_out) {
    constexpr int LK = Log2<KC>::v;
    constexpr int KCP = KC + 1;
    constexpr int TW = KC / 4;
    constexpr int NT = TW * TW;
    __shared__ __align__(16) float ps[NCH * KC];
    __shared__ __align__(16) float ts[NCH * KC];
    __shared__ float sss[KC * KCP];
    __shared__ float oss[KC * KCP];
    __shared__ float dvv[KC];
    __shared__ float rbuf[4];
    int b = blockIdx.x, tid = threadIdx.x;
    const float* pb = p + (size_t)b * NC * KC;
    const float* tb = tmp + (size_t)b * NC * KC;
    const float* db = dflat + (size_t)b * NC;
    float sa[4][4], oa[4][4];
#pragma unroll
    for (int r = 0; r < 4; ++r)
#pragma unroll
        for (int c = 0; c < 4; ++c) { sa[r][c] = 0.f; oa[r][c] = 0.f; }
    int kt = (tid < NT) ? tid / TW : 0;
    int lt = (tid < NT) ? tid % TW : 0;
    float den = 0.f;
    for (int n0 = 0; n0 < NC; n0 += NCH) {
        for (int i = tid; i < NCH * KC / 4; i += 256) {
            ((float4*)ps)[i] = ((const float4*)(pb + (size_t)n0 * KC))[i];
            ((float4*)ts)[i] = ((const float4*)(tb + (size_t)n0 * KC))[i];
        }
        __syncthreads();
        for (int i4 = tid; i4 < NCH * KC / 4; i4 += 256) {
            float4 v = ((const float4*)ps)[i4];
            float dd = db[n0 + ((i4 * 4) >> LK)];
            den += (v.x * v.x + v.y * v.y + v.z * v.z + v.w * v.w) * dd;
        }
        if (tid < NT) {
#pragma unroll 4
            for (int nn = 0; nn < NCH; ++nn) {
                float4 kv4 = *(const float4*)&ps[nn * KC + kt * 4];
                float4 lv4 = *(const float4*)&ps[nn * KC + lt * 4];
                float4 tv4 = *(const float4*)&ts[nn * KC + lt * 4];
                float kv[4] = {kv4.x, kv4.y, kv4.z, kv4.w};
                float lv[4] = {lv4.x, lv4.y, lv4.z, lv4.w};
                float tv[4] = {tv4.x, tv4.y, tv4.z, tv4.w};
#pragma unroll
                for (int r = 0; r < 4; ++r)
#pragma unroll
                    for (int c = 0; c < 4; ++c) {
                        sa[r][c] += kv[r] * lv[c];
                        oa[r][c] += kv[r] * tv[c];
                    }
            }
        }
        __syncthreads();
    }
    if (tid < NT) {
#pragma unroll
        for (int r = 0; r < 4; ++r)
#pragma unroll
            for (int c = 0; c < 4; ++c) {
                sss[(kt * 4 + r) * KCP + lt * 4 + c] = sa[r][c];
                oss[(kt * 4 + r) * KCP + lt * 4 + c] = oa[r][c];
            }
    }
    __syncthreads();
    float ssn2 = 0.f;
    for (int i = tid; i < KC * KC; i += 256) {
        int k = i >> LK, l = i & (KC - 1);
        float v = sss[k * KCP + l];
        ssn2 += v * v;
    }
    float num = 0.f;
    for (int k = tid; k < KC; k += 256) num += oss[k * KCP + k];
    float den_t = blk_sum256(den, rbuf);
    float ssn2_t = blk_sum256(ssn2, rbuf);
    float num_t = blk_sum256(num, rbuf);
    float inv = 1.0f / sqrtf(ssn2_t);
    float dk = rsqrtf((float)KC);
    float o2 = 0.f;
    for (int i = tid; i < KC * KC; i += 256) {
        int k = i >> LK, l = i & (KC - 1);
        float v = sss[k * KCP + l] * inv - ((k == l) ? dk : 0.f);
        o2 += v * v;
    }
    float o2_t = blk_sum256(o2, rbuf);
    if (tid == 0) {
        atomicAdd(mc_out, -(num_t / den_t) * (1.0f / NB));
        atomicAdd(or_out, sqrtf(o2_t) * (1.0f / NB));
    }
    if (tid < KC) {
        float rs = 0.f;
        for (int l = 0; l < KC; ++l) rs += oss[tid * KCP + l];
        rs -= oss[tid * KCP + tid];
        dvv[tid] = sqrtf(rs) + EPSV;
    }
    __syncthreads();
    for (int i = tid; i < KC * KC; i += 256) {
        int k = i >> LK, l = i & (KC - 1);
        float v = (k == l) ? 0.f : oss[k * KCP + l] / (dvv[k] * dvv[l]);
        oadj_out[(size_t)b * KC * KC + i] = v;
    }
    if (DFN && tid < KC) {
        float s = 0.f;
        for (int l = 0; l < KC; ++l)
            if (l != tid) s += oss[tid * KCP + l] / (dvv[tid] * dvv[l]);
        dfn_out[(size_t)b * KC + tid] = s;
    }
}

// Fused dense_graph_conv per (b,t): out = (adjn@x)@Wrel + brel + x@Wroot
template<int NC2, int OC>
__global__ void k_graphconv_t(const float* __restrict__ adjn, const float* __restrict__ x,
                              const float* __restrict__ Wrel, const float* __restrict__ brel,
                              const float* __restrict__ Wroot, float* __restrict__ outp) {
    constexpr int EL1 = NC2 * HC / 256;
    constexpr int EL2 = NC2 * OC / 256;
    constexpr int LOC = Log2<OC>::v;
    __shared__ __align__(16) float xs[NC2 * HC];
    __shared__ __align__(16) float as_[NC2 * NC2];
    __shared__ float c1[NC2 * HC];
    int bt = blockIdx.x;
    int b = bt >> 4;
    int tid = threadIdx.x;
    for (int i = tid; i < NC2 * HC / 4; i += 256)
        ((float4*)xs)[i] = ((const float4*)(x + (size_t)bt * NC2 * HC))[i];
    for (int i = tid; i < NC2 * NC2 / 4; i += 256)
        ((float4*)as_)[i] = ((const float4*)(adjn + (size_t)b * NC2 * NC2))[i];
    __syncthreads();
#pragma unroll
    for (int e = 0; e < EL1; ++e) {
        int idx = tid + e * 256;
        int hh = idx & 31, n = idx >> 5;
        float acc = 0.f;
#pragma unroll 8
        for (int m = 0; m < NC2; ++m) acc += as_[n * NC2 + m] * xs[m * HC + hh];
        c1[idx] = acc;
    }
    __syncthreads();
#pragma unroll
    for (int e = 0; e < EL2; ++e) {
        int idx = tid + e * 256;
        int o = idx & (OC - 1), n = idx >> LOC;
        float acc = brel[o];
#pragma unroll 8
        for (int hh = 0; hh < HC; ++hh)
            acc += c1[n * HC + hh] * Wrel[hh * OC + o] + xs[n * HC + hh] * Wroot[hh * OC + o];
        outp[(size_t)bt * NC2 * OC + idx] = acc;
    }
}

// q[b,k,m] = sum_l p2[b,k,l] * p3[b,l,m]
__global__ void k_p23(const float* __restrict__ p2, const float* __restrict__ p3,
                      float* __restrict__ q) {
    int idx = blockIdx.x * 256 + threadIdx.x;
    if (idx >= NB * 64 * 8) return;
    int m = idx & 7;
    int rest = idx >> 3;
    int k = rest % 64;
    int b = rest / 64;
    const float* p2p = p2 + ((size_t)b * 64 + k) * 32;
    const float* p3p = p3 + (size_t)b * 32 * 8 + m;
    float s = 0.f;
    for (int l = 0; l < 32; ++l) s += p2p[l] * p3p[(size_t)l * 8];
    q[idx] = s;
}

// aggout[b,n,m] = sum_k p1[b,n,k] * q[b,k,m]
__global__ void k_aggout(const float* __restrict__ p1, const float* __restrict__ q,
                         float* __restrict__ outp) {
    int idx = blockIdx.x * 256 + threadIdx.x;
    if (idx >= NB * 256 * 8) return;
    int m = idx & 7;
    int rest = idx >> 3;
    int n = rest & 255;
    int b = rest >> 8;
    const float* pp = p1 + ((size_t)b * 256 + n) * 64;
    const float* qp = q + (size_t)b * 512 + m;
    float s = 0.f;
    for (int k = 0; k < 64; ++k) s += pp[k] * qp[(size_t)k * 8];
    outp[idx] = s;
}

// ---------------- host launch ----------------

extern "C" void kernel_launch(void* const* d_in, const int* in_sizes, int n_in,
                              void* d_out, int out_size, void* d_ws, size_t ws_size,
                              hipStream_t stream) {
    const float* pos    = (const float*)d_in[0];
    const float* ea     = (const float*)d_in[1];
    const int*   esrc   = (const int*)d_in[2];
    const int*   edst   = (const int*)d_in[3];
    const float* W1     = (const float*)d_in[4];
    const float* b1     = (const float*)d_in[5];
    const float* Wp1    = (const float*)d_in[6];
    const float* bp1    = (const float*)d_in[7];
    const float* Wrel2  = (const float*)d_in[8];
    const float* brel2  = (const float*)d_in[9];
    const float* Wroot2 = (const float*)d_in[10];
    const float* Wp2    = (const float*)d_in[11];
    const float* bp2    = (const float*)d_in[12];
    const float* Wrel3  = (const float*)d_in[13];
    const float* brel3  = (const float*)d_in[14];
    const float* Wroot3 = (const float*)d_in[15];
    const float* Wp3    = (const float*)d_in[16];
    const float* bp3    = (const float*)d_in[17];
    const float* Wrel4  = (const float*)d_in[18];
    const float* brel4  = (const float*)d_in[19];
    const float* Wroot4 = (const float*)d_in[20];
    float* out = (float*)d_out;

    char* w = (char*)d_ws;
    float* ADJ0 = (float*)w;                   // 16.7 MB unweighted adj (live thru L1)
    float* WADJ = (float*)(w + 16777216);      // 16.7 MB weighted adj (dead after zgemm)
    float* X    = (float*)(w + 33554432);      // 33.5 MB : y -> TMP
    char* sp    = w + 67108864;
    float* DINV   = (float*)(sp);
    float* XM     = (float*)(sp + 65536);      // L2/L3 means only (<=512 KB)
    float* DFLAT2 = (float*)(sp + 1114112);
    float* DFLAT3 = (float*)(sp + 1130496);
    float* GDEN1  = (float*)(sp + 1146880);    // 4*64 floats
    float* GDEN2  = (float*)(sp + 1150976);    // 4*64 floats
    float* P1     = (float*)(sp + 2162688);
    float* X1A    = (float*)(sp + 6356992);    // also Z overlay (Z dead before X1A write)
    float* OADJ1  = (float*)(sp + 14745600);
    float* P2     = (float*)(sp + 15794176);
    float* OADJ2  = (float*)(sp + 16318464);
    float* P3     = (float*)(sp + 16580608);
    float* X3A    = (float*)(sp + 16646144);
    float* OADJ3  = (float*)(sp + 17694720);
    float* DFLAT  = (float*)(sp + 17727488);
    float* P23    = (float*)(sp + 17793024);
    float* Z      = X1A;
    // overlays of the dead WADJ region (after zgemm):
    float* GBUF1 = (float*)(w + 16777216);             // 4 splits * 64 b * 8192 = 8 MB
    float* X1B   = (float*)(w + 16777216);             // written AFTER finish L1
    float* X2A   = (float*)(w + 25165824);
    float* GBUF2 = (float*)(w + 29360128);             // 4 * 64 * 2048 = 2 MB
    float* X2B   = (float*)(w + 29360128);             // written AFTER finish L2
    float* TMP   = X;                                  // valid after X's last read (L1 pool)
    float* MC    = out + 524288;                       // [mincut_total, ortho_total]

    // zero ADJ0+WADJ (33.5 MB) with plain float4 stores; MC zeroed in k_init_deg
    k_zero<<<2048, 256, 0, stream>>>((float4*)ADJ0, 2097152);

    // GCN conv: deg -> weighted dense adj -> z = Wadj@pos -> fused y/mean/softmax
    k_init_deg<<<GRID(NNODES), 256, 0, stream>>>(DINV, MC);
    k_edge_deg<<<GRID(NEDGES), 256, 0, stream>>>(edst, ea, DINV);
    k_rsqrt<<<GRID(NNODES), 256, 0, stream>>>(DINV);
    k_build<<<GRID(NEDGES), 256, 0, stream>>>(esrc, edst, ea, DINV, ADJ0, WADJ);
    k_zgemm<<<NB * 4, 256, 0, stream>>>(WADJ, pos, Z);
    k_y2<<<NNODES, 512, 0, stream>>>(Z, pos, DINV, W1, b1, Wp1, bp1, X, P1);

    // ---- Level 1: Nc=256, Kc=64; x layout [N,T,H]: sb=131072, st=32, sn=512
    k_pool4<256, 64, 64, 131072, 32, 512><<<NB * 8, 256, 0, stream>>>(P1, X, X1A);
    k_adjp_t<256, 64, 128, true><<<NB * 8, 256, 0, stream>>>(ADJ0, P1, TMP, DFLAT);
    k_ssgp<256, 64, 4, 4, 8><<<NB * 4, 256, 0, stream>>>(P1, TMP, DFLAT, GBUF1, GDEN1);
    k_finish<64, 4, true><<<NB, 256, 0, stream>>>(GBUF1, GDEN1, OADJ1, DFLAT2, MC, MC + 1);
    k_graphconv_t<64, 32><<<NB * TC, 256, 0, stream>>>(OADJ1, X1A, Wrel2, brel2, Wroot2, X1B);

    // ---- Level 2: Nc=64, Kc=32; x1b layout [B,T,64,32]: sb=32768, st=2048, sn=32
    k_mean_t<<<GRID(NB * 64 * HC), 256, 0, stream>>>(X1B, XM, 64, 32768, 2048, 32);
    k_s_softmax<<<NB * 64, 64, 0, stream>>>(XM, Wp2, bp2, P2, 32);
    k_pool4<64, 32, 64, 32768, 2048, 32><<<NB * 4, 256, 0, stream>>>(P2, X1B, X2A);
    k_adjp_t<64, 32, 64, false><<<NB * 2, 256, 0, stream>>>(OADJ1, P2, TMP, DFLAT);
    k_ssgp<64, 32, 4, 2, 4><<<NB * 4, 256, 0, stream>>>(P2, TMP, DFLAT2, GBUF2, GDEN2);
    k_finish<32, 4, true><<<NB, 256, 0, stream>>>(GBUF2, GDEN2, OADJ2, DFLAT3, MC, MC + 1);
    k_graphconv_t<32, 32><<<NB * TC, 256, 0, stream>>>(OADJ2, X2A, Wrel3, brel3, Wroot3, X2B);

    // ---- Level 3: Nc=32, Kc=8; x2b layout [B,T,32,32]: sb=16384, st=1024, sn=32
    k_mean_t<<<GRID(NB * 32 * HC), 256, 0, stream>>>(X2B, XM, 32, 16384, 1024, 32);
    k_s_softmax<<<NB * 32, 64, 0, stream>>>(XM, Wp3, bp3, P3, 8);
    k_pool4<32, 8, 32, 16384, 1024, 32><<<NB, 256, 0, stream>>>(P3, X2B, X3A);
    k_adjp_t<32, 8, 32, false><<<NB, 256, 0, stream>>>(OADJ2, P3, TMP, DFLAT);
    k_post_t<32, 8, 32, false><<<NB, 256, 0, stream>>>(P3, TMP, DFLAT3, OADJ3, DFLAT3, MC, MC + 1);
    k_graphconv_t<8, 64><<<NB * TC, 256, 0, stream>>>(OADJ3, X3A, Wrel4, brel4, Wroot4, out);

    // ---- agg = p1 @ (p2 @ p3)
    k_p23<<<GRID(NB * 64 * 8), 256, 0, stream>>>(P2, P3, P23);
    k_aggout<<<GRID(NB * 256 * 8), 256, 0, stream>>>(P1, P23, out + 524290);
}

// Round 8
// 233.168 us; speedup vs baseline: 1.5845x; 1.1442x over previous
//
#include <hip/hip_runtime.h>
#include <math.h>

#define NB 64
#define TC 16
#define HC 32
#define NNODES 16384
#define NEDGES 131072
#define EPG 2048
#define EPSV 1e-15f

static inline int GRID(int n) { return (n + 255) / 256; }

template<int V> struct Log2 { static constexpr int v = 1 + Log2<V/2>::v; };
template<> struct Log2<1> { static constexpr int v = 0; };

// ---------------- GCN front-end ----------------

// block = (b, dtile of 64 d-rows). Edge-built weighted adjacency entirely in LDS:
// z[b,d,f] = dinv[d] * sum_s (sum_{e:s->d} ew) * dinv[s] * pos[b,s,f]
// Also: dtile==0 block writes dinv to global; block 0 zeros loss accumulators.
__global__ void k_zgemm2(const int* __restrict__ esrc, const int* __restrict__ edst,
                         const float* __restrict__ ea, const float* __restrict__ pos,
                         float* __restrict__ z, float* __restrict__ dinv_g,
                         float* __restrict__ mc) {
    __shared__ float dinvs[256];
    __shared__ __align__(16) float as_[64 * 36];
    __shared__ __align__(16) float bs[32 * 48];
    int b = blockIdx.x >> 2;
    int dtile = (blockIdx.x & 3) * 64;
    int tid = threadIdx.x;
    if (blockIdx.x == 0 && tid < 2) mc[tid] = 0.f;
    // edges of this graph: 8 per thread, registers (static-indexed)
    int ebase = b * EPG;
    int svr[8], dvr[8];
    float evr[8];
#pragma unroll
    for (int j = 0; j < 8; ++j) {
        int e = ebase + tid + j * 256;
        svr[j] = esrc[e] & 255;
        dvr[j] = edst[e] & 255;
        evr[j] = ea[e];
    }
    // deg = 1 (self-loop) + sum ew into dst
    dinvs[tid] = 1.0f;
    __syncthreads();
#pragma unroll
    for (int j = 0; j < 8; ++j) atomicAdd(&dinvs[dvr[j]], evr[j]);
    __syncthreads();
    float dg = dinvs[tid];
    float dv = (dg > 0.f) ? rsqrtf(dg) : 0.f;
    __syncthreads();
    dinvs[tid] = dv;
    __syncthreads();
    if (dtile == 0) dinv_g[b * 256 + tid] = dinvs[tid];
    int d = tid >> 2, q = tid & 3;
    float acc[12];
#pragma unroll
    for (int j = 0; j < 12; ++j) acc[j] = 0.f;
    const float* pbase = pos + (size_t)b * 256 * 48;
    for (int s0 = 0; s0 < 256; s0 += 32) {
        // zero A chunk
        for (int i = tid; i < 576; i += 256)
            ((float4*)as_)[i] = make_float4(0.f, 0.f, 0.f, 0.f);
        __syncthreads();
        // build A chunk from register-cached edges (raw ew)
#pragma unroll
        for (int j = 0; j < 8; ++j) {
            int dr = dvr[j] - dtile, sc = svr[j] - s0;
            if ((unsigned)dr < 64u && (unsigned)sc < 32u)
                atomicAdd(&as_[dr * 36 + sc], evr[j]);
        }
        // stage B with dinv[s] folded
        for (int i = tid; i < 384; i += 256) {
            int r = i / 12, c = i % 12;
            float4 v = *(const float4*)(pbase + (size_t)(s0 + r) * 48 + c * 4);
            float dd = dinvs[s0 + r];
            v.x *= dd; v.y *= dd; v.z *= dd; v.w *= dd;
            *(float4*)(bs + r * 48 + c * 4) = v;
        }
        __syncthreads();
#pragma unroll 8
        for (int sp = 0; sp < 32; ++sp) {
            float a = as_[d * 36 + sp];
            const float* bp = &bs[sp * 48 + q * 12];
#pragma unroll
            for (int j = 0; j < 12; ++j) acc[j] += a * bp[j];
        }
        __syncthreads();
    }
    float dd = dinvs[dtile + d];
    float* zr = z + (size_t)(b * 256 + dtile + d) * 48 + q * 12;
#pragma unroll
    for (int j = 0; j < 12; ++j) zr[j] = acc[j] * dd;
}

// Fused per-node: y = relu((z + pos*dinv^2)@W1 + b1)  [write X]
//                 xm = mean_t y ; s1 = tanh(xm@Wp1+bp1) ; p1 = softmax(s1)
__global__ __launch_bounds__(512) void k_y2(
        const float* __restrict__ z, const float* __restrict__ pos,
        const float* __restrict__ dinv, const float* __restrict__ W1,
        const float* __restrict__ b1, const float* __restrict__ Wp1,
        const float* __restrict__ bp1, float* __restrict__ y,
        float* __restrict__ p1) {
    __shared__ float ys[16][33];
    __shared__ __align__(16) float wp[32 * 64];
    __shared__ float xmv[32];
    int n = blockIdx.x;
    int tid = threadIdx.x;
    int t = tid >> 5, h = tid & 31;
    ((float4*)wp)[tid] = ((const float4*)Wp1)[tid];
    const float* zr = z + (size_t)n * 48 + t * 3;
    const float* pr = pos + (size_t)n * 48 + t * 3;
    float di = dinv[n], d2 = di * di;
    float a0 = zr[0] + pr[0] * d2;
    float a1 = zr[1] + pr[1] * d2;
    float a2 = zr[2] + pr[2] * d2;
    float v = fmaxf(a0 * W1[h] + a1 * W1[32 + h] + a2 * W1[64 + h] + b1[h], 0.f);
    y[(size_t)n * 512 + tid] = v;
    ys[t][h] = v;
    __syncthreads();
    if (tid < 32) {
        float s = 0.f;
#pragma unroll
        for (int tt = 0; tt < 16; ++tt) s += ys[tt][tid];
        xmv[tid] = s * (1.0f / 16.0f);
    }
    __syncthreads();
    if (tid < 64) {
        float acc = bp1[tid];
#pragma unroll 8
        for (int hh = 0; hh < 32; ++hh) acc += xmv[hh] * wp[hh * 64 + tid];
        float vv = tanhf(acc);
        float m = vv;
        for (int o = 32; o > 0; o >>= 1) m = fmaxf(m, __shfl_xor(m, o));
        float e = expf(vv - m);
        float s = e;
        for (int o = 32; o > 0; o >>= 1) s += __shfl_xor(s, o);
        p1[(size_t)n * 64 + tid] = e / s;
    }
}

// ---------------- level kernels ----------------

// Fused mean-over-T + tanh-linear + softmax. One wave per row, 4 rows/block.
// x layout [b][t][n][32]: row offset b*sb + n*32, t stride st.
__global__ void k_ms(const float* __restrict__ x, const float* __restrict__ Wp,
                     const float* __restrict__ bp, float* __restrict__ p,
                     int Nc, int sb, int st, int Kc) {
    __shared__ float xmr[4][32];
    int r = blockIdx.x * 4 + (threadIdx.x >> 6);
    int lane = threadIdx.x & 63;
    int w = threadIdx.x >> 6;
    int b = r / Nc, n = r % Nc;
    const float* xp = x + (size_t)b * sb + (size_t)n * 32;
    if (lane < 32) {
        float s = 0.f;
        for (int t = 0; t < TC; ++t) s += xp[(size_t)t * st + lane];
        xmr[w][lane] = s * (1.0f / TC);
    }
    __syncthreads();
    float v = -1e30f;
    if (lane < Kc) {
        float acc = bp[lane];
        for (int h = 0; h < HC; ++h) acc += xmr[w][h] * Wp[h * Kc + lane];
        v = tanhf(acc);
    }
    float m = v;
    for (int o = 32; o > 0; o >>= 1) m = fmaxf(m, __shfl_xor(m, o));
    float e = (lane < Kc) ? expf(v - m) : 0.f;
    float s = e;
    for (int o = 32; o > 0; o >>= 1) s += __shfl_xor(s, o);
    if (lane < Kc) p[(size_t)r * Kc + lane] = e / s;
}

// out[b,t,k,h] = sum_n p[(b*NC+n)*KC+k] * x[b*SB + t*STT + n*STN + h]
// register-tiled 4k x 4h per thread
template<int NC, int KC, int NCH, int SB, int STT, int STN>
__global__ void k_pool4(const float* __restrict__ p, const float* __restrict__ x,
                        float* __restrict__ outp) {
    constexpr int TPT = KC * 2;
    constexpr int TPB = 256 / TPT;
    constexpr int NTILE = TC / TPB;
    __shared__ __align__(16) float ps[NCH * KC];
    __shared__ __align__(16) float xs[TPB * NCH * HC];
    int b = blockIdx.x / NTILE;
    int t0 = (blockIdx.x % NTILE) * TPB;
    int tid = threadIdx.x;
    int th = tid / TPT;
    int r = tid % TPT;
    int k0 = (r >> 3) * 4;
    int h0 = (r & 7) * 4;
    float acc[4][4];
#pragma unroll
    for (int rr = 0; rr < 4; ++rr)
#pragma unroll
        for (int cc = 0; cc < 4; ++cc) acc[rr][cc] = 0.f;
    const float* pbase = p + (size_t)b * NC * KC;
    const float* xbase = x + (size_t)b * SB + (size_t)t0 * STT;
    for (int n0 = 0; n0 < NC; n0 += NCH) {
        for (int i = tid; i < NCH * KC / 4; i += 256)
            ((float4*)ps)[i] = ((const float4*)(pbase + (size_t)n0 * KC))[i];
        for (int i = tid; i < TPB * NCH * 8; i += 256) {
            int q = i & 7;
            int n = (i >> 3) % NCH;
            int tt = i / (NCH * 8);
            *(float4*)&xs[(tt * NCH + n) * HC + q * 4] =
                *(const float4*)(xbase + (size_t)tt * STT + (size_t)(n0 + n) * STN + q * 4);
        }
        __syncthreads();
#pragma unroll 4
        for (int n = 0; n < NCH; ++n) {
            float4 kv4 = *(const float4*)&ps[n * KC + k0];
            float4 xv4 = *(const float4*)&xs[(th * NCH + n) * HC + h0];
            float kv[4] = {kv4.x, kv4.y, kv4.z, kv4.w};
            float xv[4] = {xv4.x, xv4.y, xv4.z, xv4.w};
#pragma unroll
            for (int rr = 0; rr < 4; ++rr)
#pragma unroll
                for (int cc = 0; cc < 4; ++cc) acc[rr][cc] += kv[rr] * xv[cc];
        }
        __syncthreads();
    }
    float* ob = outp + (((size_t)(b * TC + t0 + th) * KC + k0) * HC + h0);
#pragma unroll
    for (int rr = 0; rr < 4; ++rr) {
        float4 v = {acc[rr][0], acc[rr][1], acc[rr][2], acc[rr][3]};
        *(float4*)(ob + (size_t)rr * HC) = v;
    }
}

// L1 adjacency-apply with LDS-built count matrix from edges.
// block = (b, 32-row sl tile): tmp[b,n,l] = sum_m count(n->m)*p1[b,m,l]; dflat.
__global__ void k_adjp2(const int* __restrict__ esrc, const int* __restrict__ edst,
                        const float* __restrict__ p, float* __restrict__ tmp,
                        float* __restrict__ dflat) {
    __shared__ __align__(16) float as_[32 * 260];
    __shared__ __align__(16) float ps[64 * 64];
    int b = blockIdx.x >> 3;
    int nt0 = (blockIdx.x & 7) * 32;
    int tid = threadIdx.x;
    for (int i = tid; i < 32 * 260 / 4; i += 256)
        ((float4*)as_)[i] = make_float4(0.f, 0.f, 0.f, 0.f);
    __syncthreads();
    int ebase = b * EPG;
#pragma unroll
    for (int j = 0; j < 8; ++j) {
        int e = ebase + tid + j * 256;
        int sv = esrc[e] & 255;
        int nr = sv - nt0;
        if ((unsigned)nr < 32u)
            atomicAdd(&as_[nr * 260 + (edst[e] & 255)], 1.0f);
    }
    __syncthreads();
    int n = tid >> 3, l0 = (tid & 7) * 8;
    float acc[8];
#pragma unroll
    for (int j = 0; j < 8; ++j) acc[j] = 0.f;
    float rs = 0.f;
    for (int m0 = 0; m0 < 256; m0 += 64) {
        for (int i = tid; i < 64 * 64 / 4; i += 256)
            ((float4*)ps)[i] = ((const float4*)(p + ((size_t)b * 256 + m0) * 64))[i];
        __syncthreads();
#pragma unroll 4
        for (int m = 0; m < 64; ++m) {
            float av = as_[n * 260 + m0 + m];
            rs += av;
            float4 p0 = *(const float4*)&ps[m * 64 + l0];
            float4 p1v = *(const float4*)&ps[m * 64 + l0 + 4];
            acc[0] += av * p0.x; acc[1] += av * p0.y; acc[2] += av * p0.z; acc[3] += av * p0.w;
            acc[4] += av * p1v.x; acc[5] += av * p1v.y; acc[6] += av * p1v.z; acc[7] += av * p1v.w;
        }
        __syncthreads();
    }
#pragma unroll
    for (int j = 0; j < 8; ++j)
        tmp[((size_t)b * 256 + nt0 + n) * 64 + l0 + j] = acc[j];
    if ((tid & 7) == 0) dflat[(size_t)b * 256 + nt0 + n] = rs;
}

// dense adjacency-apply for L2/L3 (adj = normalized dense out_adj)
template<int NC, int KC, int MCH>
__global__ void k_adjp_t(const float* __restrict__ adj, const float* __restrict__ p,
                         float* __restrict__ tmp) {
    constexpr int LPT = KC / 8;
    constexpr int MROW = MCH + 4;
    constexpr int MQ = MCH / 4;
    constexpr int NBK = NC / 32;
    __shared__ __align__(16) float ps[MCH * KC];
    __shared__ __align__(16) float as_[32 * MROW];
    int b = blockIdx.x / NBK;
    int nt0 = (blockIdx.x % NBK) * 32;
    int tid = threadIdx.x;
    int n = tid >> 3;
    int l0 = (tid & 7) * LPT;
    float acc[LPT];
#pragma unroll
    for (int j = 0; j < LPT; ++j) acc[j] = 0.f;
    for (int m0 = 0; m0 < NC; m0 += MCH) {
        for (int i = tid; i < MCH * KC / 4; i += 256)
            ((float4*)ps)[i] = ((const float4*)(p + ((size_t)b * NC + m0) * KC))[i];
        for (int i = tid; i < 32 * MQ; i += 256) {
            int r = i / MQ, q = i % MQ;
            ((float4*)(as_ + r * MROW))[q] =
                ((const float4*)(adj + ((size_t)b * NC + nt0 + r) * NC + m0))[q];
        }
        __syncthreads();
#pragma unroll 4
        for (int m = 0; m < MCH; ++m) {
            float av = as_[n * MROW + m];
#pragma unroll
            for (int j = 0; j < LPT; ++j) acc[j] += av * ps[m * KC + l0 + j];
        }
        __syncthreads();
    }
#pragma unroll
    for (int j = 0; j < LPT; ++j)
        tmp[((size_t)b * NC + nt0 + n) * KC + l0 + j] = acc[j];
}

__device__ inline float blk_sum256(float v, float* rbuf) {
    for (int o = 32; o > 0; o >>= 1) v += __shfl_xor(v, o);
    __syncthreads();
    if ((threadIdx.x & 63) == 0) rbuf[threadIdx.x >> 6] = v;
    __syncthreads();
    return rbuf[0] + rbuf[1] + rbuf[2] + rbuf[3];
}

// Partial GEMM, no atomics: G[split][b] = p_chunk^T @ [p_chunk | tmp_chunk]
template<int NC, int KC, int NSPLIT, int KT, int LT>
__global__ void k_ssgp(const float* __restrict__ p, const float* __restrict__ tmp,
                       const float* __restrict__ dflat, float* __restrict__ G,
                       float* __restrict__ Gden) {
    constexpr int NCH = NC / NSPLIT;
    constexpr int LC = 2 * KC;
    constexpr int KQ = KC / 4;
    __shared__ __align__(16) float ab[NCH * LC];
    __shared__ float rbuf[4];
    int b = blockIdx.x / NSPLIT;
    int split = blockIdx.x % NSPLIT;
    int n0 = split * NCH;
    int tid = threadIdx.x;
    const float* pb = p + ((size_t)b * NC + n0) * KC;
    const float* tb = tmp + ((size_t)b * NC + n0) * KC;
    const float* db = dflat + (size_t)b * NC + n0;
    for (int i = tid; i < NCH * KQ; i += 256) {
        int r = i / KQ, c = i % KQ;
        *(float4*)(ab + r * LC + c * 4) = ((const float4*)pb)[i];
        *(float4*)(ab + r * LC + KC + c * 4) = ((const float4*)tb)[i];
    }
    __syncthreads();
    float den = 0.f;
    for (int i = tid; i < NCH * KQ; i += 256) {
        int r = i / KQ, c = i % KQ;
        float4 v = *(const float4*)(ab + r * LC + c * 4);
        den += (v.x * v.x + v.y * v.y + v.z * v.z + v.w * v.w) * db[r];
    }
    int kt = tid >> 4, lt = tid & 15;
    int k0 = kt * KT, l0 = lt * LT;
    float acc[KT][LT];
#pragma unroll
    for (int r = 0; r < KT; ++r)
#pragma unroll
        for (int c = 0; c < LT; ++c) acc[r][c] = 0.f;
#pragma unroll 4
    for (int n = 0; n < NCH; ++n) {
        float kv[KT], lv[LT];
#pragma unroll
        for (int r = 0; r < KT; ++r) kv[r] = ab[n * LC + k0 + r];
#pragma unroll
        for (int c = 0; c < LT; ++c) lv[c] = ab[n * LC + l0 + c];
#pragma unroll
        for (int r = 0; r < KT; ++r)
#pragma unroll
            for (int c = 0; c < LT; ++c) acc[r][c] += kv[r] * lv[c];
    }
    float* Gb = G + ((size_t)split * NB + b) * (KC * LC);
#pragma unroll
    for (int r = 0; r < KT; ++r)
#pragma unroll
        for (int c = 0; c < LT; ++c)
            Gb[(k0 + r) * LC + l0 + c] = acc[r][c];
    float dt = blk_sum256(den, rbuf);
    if (tid == 0) Gden[(size_t)split * NB + b] = dt;
}

// Per-batch finish: sum NSPLIT partials, losses, zero-diag+normalize, next dflat
template<int KC, int NSPLIT, bool DFN>
__global__ void k_finish(const float* __restrict__ G, const float* __restrict__ Gden,
                         float* __restrict__ oadj_out, float* __restrict__ dfn_out,
                         float* __restrict__ mc_out, float* __restrict__ or_out) {
    constexpr int LK = Log2<KC>::v;
    constexpr int KCP = KC + 1;
    constexpr int LC = 2 * KC;
    __shared__ float sss[KC * KCP];
    __shared__ float oss[KC * KCP];
    __shared__ float dvv[KC];
    __shared__ float rbuf[4];
    int b = blockIdx.x, tid = threadIdx.x;
    for (int i = tid; i < KC * KC; i += 256) {
        int k = i >> LK, l = i & (KC - 1);
        float sv = 0.f, ov = 0.f;
#pragma unroll
        for (int s = 0; s < NSPLIT; ++s) {
            const float* Gb = G + ((size_t)s * NB + b) * KC * LC;
            sv += Gb[k * LC + l];
            ov += Gb[k * LC + KC + l];
        }
        sss[k * KCP + l] = sv;
        oss[k * KCP + l] = ov;
    }
    __syncthreads();
    float ssn2 = 0.f;
    for (int i = tid; i < KC * KC; i += 256) {
        int k = i >> LK, l = i & (KC - 1);
        float v = sss[k * KCP + l];
        ssn2 += v * v;
    }
    float num = 0.f;
    for (int k = tid; k < KC; k += 256) num += oss[k * KCP + k];
    float ssn2_t = blk_sum256(ssn2, rbuf);
    float num_t = blk_sum256(num, rbuf);
    float den_t = 0.f;
#pragma unroll
    for (int s = 0; s < NSPLIT; ++s) den_t += Gden[(size_t)s * NB + b];
    float inv = 1.0f / sqrtf(ssn2_t);
    float dk = rsqrtf((float)KC);
    float o2 = 0.f;
    for (int i = tid; i < KC * KC; i += 256) {
        int k = i >> LK, l = i & (KC - 1);
        float v = sss[k * KCP + l] * inv - ((k == l) ? dk : 0.f);
        o2 += v * v;
    }
    float o2_t = blk_sum256(o2, rbuf);
    if (tid == 0) {
        atomicAdd(mc_out, -(num_t / den_t) * (1.0f / NB));
        atomicAdd(or_out, sqrtf(o2_t) * (1.0f / NB));
    }
    if (tid < KC) {
        float rs = 0.f;
        for (int l = 0; l < KC; ++l) rs += oss[tid * KCP + l];
        rs -= oss[tid * KCP + tid];
        dvv[tid] = sqrtf(rs) + EPSV;
    }
    __syncthreads();
    for (int i = tid; i < KC * KC; i += 256) {
        int k = i >> LK, l = i & (KC - 1);
        float v = (k == l) ? 0.f : oss[k * KCP + l] / (dvv[k] * dvv[l]);
        oadj_out[(size_t)b * KC * KC + i] = v;
    }
    if (DFN && tid < KC) {
        float s = 0.f;
        for (int l = 0; l < KC; ++l)
            if (l != tid) s += oss[tid * KCP + l] / (dvv[tid] * dvv[l]);
        dfn_out[(size_t)b * KC + tid] = s;
    }
}

// single-block post for tiny L3 (Nc=32, Kc=8)
template<int NC, int KC, int NCH, bool DFN>
__global__ void k_post_t(const float* __restrict__ p, const float* __restrict__ tmp,
                         const float* __restrict__ dflat, float* __restrict__ oadj_out,
                         float* __restrict__ dfn_out, float* __restrict__ mc_out,
                         float* __restrict__ or_out) {
    constexpr int LK = Log2<KC>::v;
    constexpr int KCP = KC + 1;
    constexpr int TW = KC / 4;
    constexpr int NT = TW * TW;
    __shared__ __align__(16) float ps[NCH * KC];
    __shared__ __align__(16) float ts[NCH * KC];
    __shared__ float sss[KC * KCP];
    __shared__ float oss[KC * KCP];
    __shared__ float dvv[KC];
    __shared__ float rbuf[4];
    int b = blockIdx.x, tid = threadIdx.x;
    const float* pb = p + (size_t)b * NC * KC;
    const float* tb = tmp + (size_t)b * NC * KC;
    const float* db = dflat + (size_t)b * NC;
    float sa[4][4], oa[4][4];
#pragma unroll
    for (int r = 0; r < 4; ++r)
#pragma unroll
        for (int c = 0; c < 4; ++c) { sa[r][c] = 0.f; oa[r][c] = 0.f; }
    int kt = (tid < NT) ? tid / TW : 0;
    int lt = (tid < NT) ? tid % TW : 0;
    float den = 0.f;
    for (int n0 = 0; n0 < NC; n0 += NCH) {
        for (int i = tid; i < NCH * KC / 4; i += 256) {
            ((float4*)ps)[i] = ((const float4*)(pb + (size_t)n0 * KC))[i];
            ((float4*)ts)[i] = ((const float4*)(tb + (size_t)n0 * KC))[i];
        }
        __syncthreads();
        for (int i4 = tid; i4 < NCH * KC / 4; i4 += 256) {
            float4 v = ((const float4*)ps)[i4];
            float dd = db[n0 + ((i4 * 4) >> LK)];
            den += (v.x * v.x + v.y * v.y + v.z * v.z + v.w * v.w) * dd;
        }
        if (tid < NT) {
#pragma unroll 4
            for (int nn = 0; nn < NCH; ++nn) {
                float4 kv4 = *(const float4*)&ps[nn * KC + kt * 4];
                float4 lv4 = *(const float4*)&ps[nn * KC + lt * 4];
                float4 tv4 = *(const float4*)&ts[nn * KC + lt * 4];
                float kv[4] = {kv4.x, kv4.y, kv4.z, kv4.w};
                float lv[4] = {lv4.x, lv4.y, lv4.z, lv4.w};
                float tv[4] = {tv4.x, tv4.y, tv4.z, tv4.w};
#pragma unroll
                for (int r = 0; r < 4; ++r)
#pragma unroll
                    for (int c = 0; c < 4; ++c) {
                        sa[r][c] += kv[r] * lv[c];
                        oa[r][c] += kv[r] * tv[c];
                    }
            }
        }
        __syncthreads();
    }
    if (tid < NT) {
#pragma unroll
        for (int r = 0; r < 4; ++r)
#pragma unroll
            for (int c = 0; c < 4; ++c) {
                sss[(kt * 4 + r) * KCP + lt * 4 + c] = sa[r][c];
                oss[(kt * 4 + r) * KCP + lt * 4 + c] = oa[r][c];
            }
    }
    __syncthreads();
    float ssn2 = 0.f;
    for (int i = tid; i < KC * KC; i += 256) {
        int k = i >> LK, l = i & (KC - 1);
        float v = sss[k * KCP + l];
        ssn2 += v * v;
    }
    float num = 0.f;
    for (int k = tid; k < KC; k += 256) num += oss[k * KCP + k];
    float den_t = blk_sum256(den, rbuf);
    float ssn2_t = blk_sum256(ssn2, rbuf);
    float num_t = blk_sum256(num, rbuf);
    float inv = 1.0f / sqrtf(ssn2_t);
    float dk = rsqrtf((float)KC);
    float o2 = 0.f;
    for (int i = tid; i < KC * KC; i += 256) {
        int k = i >> LK, l = i & (KC - 1);
        float v = sss[k * KCP + l] * inv - ((k == l) ? dk : 0.f);
        o2 += v * v;
    }
    float o2_t = blk_sum256(o2, rbuf);
    if (tid == 0) {
        atomicAdd(mc_out, -(num_t / den_t) * (1.0f / NB));
        atomicAdd(or_out, sqrtf(o2_t) * (1.0f / NB));
    }
    if (tid < KC) {
        float rs = 0.f;
        for (int l = 0; l < KC; ++l) rs += oss[tid * KCP + l];
        rs -= oss[tid * KCP + tid];
        dvv[tid] = sqrtf(rs) + EPSV;
    }
    __syncthreads();
    for (int i = tid; i < KC * KC; i += 256) {
        int k = i >> LK, l = i & (KC - 1);
        float v = (k == l) ? 0.f : oss[k * KCP + l] / (dvv[k] * dvv[l]);
        oadj_out[(size_t)b * KC * KC + i] = v;
    }
    if (DFN && tid < KC) {
        float s = 0.f;
        for (int l = 0; l < KC; ++l)
            if (l != tid) s += oss[tid * KCP + l] / (dvv[tid] * dvv[l]);
        dfn_out[(size_t)b * KC + tid] = s;
    }
}

// Fused dense_graph_conv per (b,t): out = (adjn@x)@Wrel + brel + x@Wroot
template<int NC2, int OC>
__global__ void k_graphconv_t(const float* __restrict__ adjn, const float* __restrict__ x,
                              const float* __restrict__ Wrel, const float* __restrict__ brel,
                              const float* __restrict__ Wroot, float* __restrict__ outp) {
    constexpr int EL1 = NC2 * HC / 256;
    constexpr int EL2 = NC2 * OC / 256;
    constexpr int LOC = Log2<OC>::v;
    __shared__ __align__(16) float xs[NC2 * HC];
    __shared__ __align__(16) float as_[NC2 * NC2];
    __shared__ float c1[NC2 * HC];
    int bt = blockIdx.x;
    int b = bt >> 4;
    int tid = threadIdx.x;
    for (int i = tid; i < NC2 * HC / 4; i += 256)
        ((float4*)xs)[i] = ((const float4*)(x + (size_t)bt * NC2 * HC))[i];
    for (int i = tid; i < NC2 * NC2 / 4; i += 256)
        ((float4*)as_)[i] = ((const float4*)(adjn + (size_t)b * NC2 * NC2))[i];
    __syncthreads();
#pragma unroll
    for (int e = 0; e < EL1; ++e) {
        int idx = tid + e * 256;
        int hh = idx & 31, n = idx >> 5;
        float acc = 0.f;
#pragma unroll 8
        for (int m = 0; m < NC2; ++m) acc += as_[n * NC2 + m] * xs[m * HC + hh];
        c1[idx] = acc;
    }
    __syncthreads();
#pragma unroll
    for (int e = 0; e < EL2; ++e) {
        int idx = tid + e * 256;
        int o = idx & (OC - 1), n = idx >> LOC;
        float acc = brel[o];
#pragma unroll 8
        for (int hh = 0; hh < HC; ++hh)
            acc += c1[n * HC + hh] * Wrel[hh * OC + o] + xs[n * HC + hh] * Wroot[hh * OC + o];
        outp[(size_t)bt * NC2 * OC + idx] = acc;
    }
}

// Fused agg: q = p2@p3 (LDS), out = p1@q. One block per batch.
__global__ void k_p23agg(const float* __restrict__ p1, const float* __restrict__ p2,
                         const float* __restrict__ p3, float* __restrict__ outp) {
    __shared__ float p3s[32 * 8];
    __shared__ float qs[64 * 8];
    int b = blockIdx.x, tid = threadIdx.x;
    p3s[tid] = p3[(size_t)b * 256 + tid];
    __syncthreads();
    for (int i = tid; i < 512; i += 256) {
        int k = i >> 3, m = i & 7;
        const float* p2r = p2 + ((size_t)b * 64 + k) * 32;
        float s = 0.f;
        for (int l = 0; l < 32; ++l) s += p2r[l] * p3s[l * 8 + m];
        qs[i] = s;
    }
    __syncthreads();
    float acc[8];
#pragma unroll
    for (int m = 0; m < 8; ++m) acc[m] = 0.f;
    const float* p1r = p1 + ((size_t)b * 256 + tid) * 64;
    for (int k = 0; k < 64; ++k) {
        float pv = p1r[k];
#pragma unroll
        for (int m = 0; m < 8; ++m) acc[m] += pv * qs[k * 8 + m];
    }
#pragma unroll
    for (int m = 0; m < 8; ++m)
        outp[((size_t)b * 256 + tid) * 8 + m] = acc[m];
}

// ---------------- host launch ----------------

extern "C" void kernel_launch(void* const* d_in, const int* in_sizes, int n_in,
                              void* d_out, int out_size, void* d_ws, size_t ws_size,
                              hipStream_t stream) {
    const float* pos    = (const float*)d_in[0];
    const float* ea     = (const float*)d_in[1];
    const int*   esrc   = (const int*)d_in[2];
    const int*   edst   = (const int*)d_in[3];
    const float* W1     = (const float*)d_in[4];
    const float* b1     = (const float*)d_in[5];
    const float* Wp1    = (const float*)d_in[6];
    const float* bp1    = (const float*)d_in[7];
    const float* Wrel2  = (const float*)d_in[8];
    const float* brel2  = (const float*)d_in[9];
    const float* Wroot2 = (const float*)d_in[10];
    const float* Wp2    = (const float*)d_in[11];
    const float* bp2    = (const float*)d_in[12];
    const float* Wrel3  = (const float*)d_in[13];
    const float* brel3  = (const float*)d_in[14];
    const float* Wroot3 = (const float*)d_in[15];
    const float* Wp3    = (const float*)d_in[16];
    const float* bp3    = (const float*)d_in[17];
    const float* Wrel4  = (const float*)d_in[18];
    const float* brel4  = (const float*)d_in[19];
    const float* Wroot4 = (const float*)d_in[20];
    float* out = (float*)d_out;

    char* w = (char*)d_ws;
    float* X    = (float*)(w + 33554432);      // 33.5 MB : y -> TMP
    char* sp    = w + 67108864;
    float* DINV   = (float*)(sp);
    float* DFLAT2 = (float*)(sp + 1114112);
    float* DFLAT3 = (float*)(sp + 1130496);
    float* GDEN1  = (float*)(sp + 1146880);
    float* GDEN2  = (float*)(sp + 1150976);
    float* P1     = (float*)(sp + 2162688);
    float* X1A    = (float*)(sp + 6356992);    // Z overlay (Z dead before X1A write)
    float* OADJ1  = (float*)(sp + 14745600);
    float* P2     = (float*)(sp + 15794176);
    float* OADJ2  = (float*)(sp + 16318464);
    float* P3     = (float*)(sp + 16580608);
    float* X3A    = (float*)(sp + 16646144);
    float* OADJ3  = (float*)(sp + 17694720);
    float* DFLAT  = (float*)(sp + 17727488);
    float* Z      = X1A;
    // overlays in w[0 .. 33.5MB) (adjacencies no longer materialized):
    float* GBUF1 = (float*)(w + 16777216);             // 4*64*8192 = 8 MB
    float* X1B   = (float*)(w + 16777216);             // written AFTER finish L1
    float* X2A   = (float*)(w + 25165824);
    float* GBUF2 = (float*)(w + 29360128);             // 4*64*2048 = 512 KB
    float* X2B   = (float*)(w + 29360128);             // written AFTER finish L2
    float* TMP   = X;                                  // valid after X's last read
    float* MC    = out + 524288;                       // [mincut_total, ortho_total]

    // GCN: edge-built LDS adjacency -> z -> fused y/mean/softmax (MC zeroed in zgemm2)
    k_zgemm2<<<NB * 4, 256, 0, stream>>>(esrc, edst, ea, pos, Z, DINV, MC);
    k_y2<<<NNODES, 512, 0, stream>>>(Z, pos, DINV, W1, b1, Wp1, bp1, X, P1);

    // ---- Level 1: Nc=256, Kc=64; x layout [N,T,H]: sb=131072, st=32, sn=512
    k_pool4<256, 64, 64, 131072, 32, 512><<<NB * 8, 256, 0, stream>>>(P1, X, X1A);
    k_adjp2<<<NB * 8, 256, 0, stream>>>(esrc, edst, P1, TMP, DFLAT);
    k_ssgp<256, 64, 4, 4, 8><<<NB * 4, 256, 0, stream>>>(P1, TMP, DFLAT, GBUF1, GDEN1);
    k_finish<64, 4, true><<<NB, 256, 0, stream>>>(GBUF1, GDEN1, OADJ1, DFLAT2, MC, MC + 1);
    k_graphconv_t<64, 32><<<NB * TC, 256, 0, stream>>>(OADJ1, X1A, Wrel2, brel2, Wroot2, X1B);

    // ---- Level 2: Nc=64, Kc=32; x1b layout [B,T,64,32]: sb=32768, st=2048
    k_ms<<<NB * 64 / 4, 256, 0, stream>>>(X1B, Wp2, bp2, P2, 64, 32768, 2048, 32);
    k_pool4<64, 32, 64, 32768, 2048, 32><<<NB * 4, 256, 0, stream>>>(P2, X1B, X2A);
    k_adjp_t<64, 32, 64><<<NB * 2, 256, 0, stream>>>(OADJ1, P2, TMP);
    k_ssgp<64, 32, 4, 2, 4><<<NB * 4, 256, 0, stream>>>(P2, TMP, DFLAT2, GBUF2, GDEN2);
    k_finish<32, 4, true><<<NB, 256, 0, stream>>>(GBUF2, GDEN2, OADJ2, DFLAT3, MC, MC + 1);
    k_graphconv_t<32, 32><<<NB * TC, 256, 0, stream>>>(OADJ2, X2A, Wrel3, brel3, Wroot3, X2B);

    // ---- Level 3: Nc=32, Kc=8; x2b layout [B,T,32,32]: sb=16384, st=1024
    k_ms<<<NB * 32 / 4, 256, 0, stream>>>(X2B, Wp3, bp3, P3, 32, 16384, 1024, 8);
    k_pool4<32, 8, 32, 16384, 1024, 32><<<NB, 256, 0, stream>>>(P3, X2B, X3A);
    k_adjp_t<32, 8, 32><<<NB, 256, 0, stream>>>(OADJ2, P3, TMP);
    k_post_t<32, 8, 32, false><<<NB, 256, 0, stream>>>(P3, TMP, DFLAT3, OADJ3, DFLAT3, MC, MC + 1);
    k_graphconv_t<8, 64><<<NB * TC, 256, 0, stream>>>(OADJ3, X3A, Wrel4, brel4, Wroot4, out);

    // ---- agg = p1 @ (p2 @ p3), fused
    k_p23agg<<<NB, 256, 0, stream>>>(P1, P2, P3, out + 524290);
}